// Round 15
// baseline (1707.881 us; speedup 1.0000x reference)
//
#include <hip/hip_runtime.h>

#define N_NODES 50000
#define N_EDGES 200000
#define N_GRAPHS 2048
#define HDIM 300
#define HDIM2 600
#define NLAYER 5
// padded dims for MFMA
#define K1P 320     // GEMM1 K (300 -> 320), h/zin/z2 storage stride
#define N1P 640     // GEMM1 N (600 -> 640), also GEMM2 K
#define N2P 384     // GEMM2 N tile coverage (300 -> 384)

#define MT1 ((N_NODES + 127) / 128)   // 391 m-tiles
#define NWG1 (5 * MT1)                // 1955
#define NWG2 (3 * MT1)                // 1173

#define NCOMBO 4096                   // 16^3 bond-attr combos

#define SCAN_BLK 1024
#define NSCAN ((N_NODES + SCAN_BLK - 1) / SCAN_BLK)   // 49

typedef __attribute__((ext_vector_type(8))) _Float16 f16x8;
typedef __attribute__((ext_vector_type(8))) unsigned short ushort8;
typedef __attribute__((ext_vector_type(4))) float f32x4;

__device__ __forceinline__ unsigned short f2h(float f) {
    _Float16 h = (_Float16)f;                      // RNE
    return __builtin_bit_cast(unsigned short, h);
}
__device__ __forceinline__ float h2f(unsigned short u) {
    _Float16 h = __builtin_bit_cast(_Float16, u);
    return (float)h;
}

__device__ __forceinline__ int lower_bound_i(const int* a, int n, int key) {
    int lo = 0, hi = n;
    while (lo < hi) { int mid = (lo + hi) >> 1; if (a[mid] < key) lo = mid + 1; else hi = mid; }
    return lo;
}

// bijective XCD chunking (m204)
__device__ __forceinline__ int xcd_swz(int orig, int nwg) {
    int q = nwg >> 3, r = nwg & 7;
    int xcd = orig & 7;
    int base = (xcd < r) ? xcd * (q + 1) : r * (q + 1) + (xcd - r) * q;
    return base + (orig >> 3);
}

// ---------- init ----------
__global__ void k_init(int* deg, int* fill, float* s1, float* q1, float* s2, float* q2) {
    int i = blockIdx.x * blockDim.x + threadIdx.x;
    if (i < N_NODES) { deg[i] = 0; fill[i] = 0; }
    if (i < N1P)     { s1[i] = 0.f; q1[i] = 0.f; }
    if (i < K1P)     { s2[i] = 0.f; q2[i] = 0.f; }
}

// ---------- atom encoder ----------
__global__ void k_atom(const int* __restrict__ x, const float* __restrict__ atom_emb,
                       unsigned short* __restrict__ hf) {
    int idx = blockIdx.x * blockDim.x + threadIdx.x;
    if (idx >= N_NODES * K1P) return;
    int n = idx / K1P;
    int c = idx - n * K1P;
    if (c >= HDIM) { hf[idx] = 0; return; }
    const int* xr = x + n * 9;
    float acc = 0.f;
#pragma unroll
    for (int f = 0; f < 9; ++f) {
        int row = xr[f] + f * 128;
        acc += atom_emb[(size_t)row * HDIM + c];
    }
    hf[idx] = f2h(acc);
}

// ---------- bond combo table ----------
__global__ void k_ecomb(const float* __restrict__ bond_emb, unsigned short* __restrict__ ecomb) {
    int t = blockIdx.x * blockDim.x + threadIdx.x;
    if (t >= NCOMBO * HDIM) return;
    int idx = t / HDIM, c = t - idx * HDIM;
    int a0 = idx & 15, a1 = (idx >> 4) & 15, a2 = idx >> 8;
    float v = bond_emb[(size_t)a0 * HDIM + c]
            + bond_emb[(size_t)(16 + a1) * HDIM + c]
            + bond_emb[(size_t)(32 + a2) * HDIM + c];
    ecomb[t] = f2h(v);
}

// ---------- CSR build over dst ----------
__global__ void k_deg(const int* __restrict__ dst, int* deg) {
    int j = blockIdx.x * blockDim.x + threadIdx.x;
    if (j < N_EDGES) atomicAdd(&deg[dst[j]], 1);
}

__global__ void k_scan1(const int* __restrict__ deg, int* __restrict__ part,
                        int* __restrict__ psum) {
    __shared__ int buf[SCAN_BLK];
    int b = blockIdx.x, tid = threadIdx.x;
    int i = b * SCAN_BLK + tid;
    int v = (i < N_NODES) ? deg[i] : 0;
    buf[tid] = v;
    __syncthreads();
    for (int off = 1; off < SCAN_BLK; off <<= 1) {
        int t = (tid >= off) ? buf[tid - off] : 0;
        __syncthreads();
        buf[tid] += t;
        __syncthreads();
    }
    if (i < N_NODES) part[i] = buf[tid];
    if (tid == SCAN_BLK - 1) psum[b] = buf[tid];
}

__global__ void k_scan2(int* __restrict__ psum) {
    __shared__ int buf[64];
    int tid = threadIdx.x;
    int v = (tid < NSCAN) ? psum[tid] : 0;
    buf[tid] = v;
    __syncthreads();
    for (int off = 1; off < 64; off <<= 1) {
        int t = (tid >= off) ? buf[tid - off] : 0;
        __syncthreads();
        buf[tid] += t;
        __syncthreads();
    }
    if (tid < NSCAN) psum[tid] = buf[tid] - v;
}

__global__ void k_scan3(const int* __restrict__ part, const int* __restrict__ psum,
                        int* __restrict__ rowptr) {
    int i = blockIdx.x * blockDim.x + threadIdx.x;
    if (i == 0) rowptr[0] = 0;
    if (i < N_NODES) rowptr[i + 1] = part[i] + psum[i / SCAN_BLK];
}

// fill packed CSR records: int2 {src, combo idx}
__global__ void k_fill(const int* __restrict__ src, const int* __restrict__ dst,
                       const int* __restrict__ eattr, const int* __restrict__ rowptr,
                       int* fill, int2* __restrict__ csr_rec) {
    int j = blockIdx.x * blockDim.x + threadIdx.x;
    if (j < N_EDGES) {
        int d = dst[j];
        int p = atomicAdd(&fill[d], 1);
        int pos = rowptr[d] + p;
        int combo = eattr[j * 3 + 0] | (eattr[j * 3 + 1] << 4) | (eattr[j * 3 + 2] << 8);
        csr_rec[pos] = make_int2(src[j], combo);
    }
}

// ---------- weight transpose + f16 convert ----------
__global__ void k_wconv(const float* __restrict__ W, unsigned short* __restrict__ Bt,
                        int K, int NC, int KPAD, int NPAD) {
    int idx = blockIdx.x * blockDim.x + threadIdx.x;
    int tot = NLAYER * NPAD * KPAD;
    if (idx >= tot) return;
    int l = idx / (NPAD * KPAD);
    int rem = idx - l * NPAD * KPAD;
    int n = rem / KPAD;
    int k = rem - n * KPAD;
    float v = (k < K && n < NC) ? W[((size_t)l * K + k) * NC + n] : 0.f;
    Bt[idx] = f2h(v);
}

// ---------- message passing: one node per wave, 4 waves/block ----------
template <bool BN>
__global__ __launch_bounds__(256) void k_msg(const unsigned short* __restrict__ hsrc,
                                             const float* __restrict__ sc,
                                             const float* __restrict__ sh,
                                             const int* __restrict__ rowptr,
                                             const int2* __restrict__ csr_rec,
                                             const unsigned short* __restrict__ ecomb,
                                             unsigned short* __restrict__ zin) {
    int wid = threadIdx.x >> 6, lane = threadIdx.x & 63;
    int n = blockIdx.x * 4 + wid;
    if (n >= N_NODES) return;

    float scv[5], shv[5], acc[5];
#pragma unroll
    for (int q = 0; q < 5; ++q) {
        int c = lane + 64 * q;
        scv[q] = 0.f; shv[q] = 0.f; acc[q] = 0.f;
        if (c < HDIM) {
            if (BN) { scv[q] = sc[c]; shv[q] = sh[c]; }
            float v = h2f(hsrc[(size_t)n * K1P + c]);
            if (BN) v = fmaxf(v * scv[q] + shv[q], 0.f);
            acc[q] = v;
        }
    }

    int beg = rowptr[n], end = rowptr[n + 1];
    int p = beg;
    for (; p + 2 <= end; p += 2) {
        int2 r0 = csr_rec[p];
        int2 r1 = csr_rec[p + 1];
        const unsigned short* h0 = hsrc + (size_t)r0.x * K1P;
        const unsigned short* h1 = hsrc + (size_t)r1.x * K1P;
        const unsigned short* e0 = ecomb + (size_t)r0.y * HDIM;
        const unsigned short* e1 = ecomb + (size_t)r1.y * HDIM;
#pragma unroll
        for (int q = 0; q < 5; ++q) {
            int c = lane + 64 * q;
            if (c < HDIM) {
                float v0 = h2f(h0[c]);
                float v1 = h2f(h1[c]);
                if (BN) {
                    v0 = fmaxf(v0 * scv[q] + shv[q], 0.f);
                    v1 = fmaxf(v1 * scv[q] + shv[q], 0.f);
                }
                float m0 = v0 + h2f(e0[c]);
                float m1 = v1 + h2f(e1[c]);
                acc[q] += fmaxf(m0, 0.f) + fmaxf(m1, 0.f);
            }
        }
    }
    if (p < end) {
        int2 r0 = csr_rec[p];
        const unsigned short* h0 = hsrc + (size_t)r0.x * K1P;
        const unsigned short* e0 = ecomb + (size_t)r0.y * HDIM;
#pragma unroll
        for (int q = 0; q < 5; ++q) {
            int c = lane + 64 * q;
            if (c < HDIM) {
                float v0 = h2f(h0[c]);
                if (BN) v0 = fmaxf(v0 * scv[q] + shv[q], 0.f);
                float m0 = v0 + h2f(e0[c]);
                acc[q] += fmaxf(m0, 0.f);
            }
        }
    }
    unsigned short* zr = zin + (size_t)n * K1P;
#pragma unroll
    for (int q = 0; q < 5; ++q) {
        int c = lane + 64 * q;
        if (c < HDIM) zr[c] = f2h(acc[q]);
    }
}

// ---------- GEMM1: barrier-free per-wave direct-load, 128x128 block / 64x64 per wave ----------
// No LDS staging; each wave loads its own A/B fragments from global (L2-hot),
// 2x-unrolled register double-buffer: prefetch phase t+1 while MFMA phase t.
__global__ __launch_bounds__(256, 2) void k_mfma1(const unsigned short* __restrict__ A,
                                                  const unsigned short* __restrict__ Bt,
                                                  const float* __restrict__ bias,
                                                  unsigned short* __restrict__ Ch,
                                                  float* __restrict__ gsum,
                                                  float* __restrict__ gssq) {
    __shared__ float csum[128], cssq[128];

    const int tid = threadIdx.x;
    const int lane = tid & 63, wid = tid >> 6;
    const int wm = wid >> 1, wn = wid & 1;
    const int wgid = xcd_swz(blockIdx.x, NWG1);
    const int n0 = (wgid % 5) * 128, m0 = (wgid / 5) * 128;
    const int fr = lane & 15, fq = lane >> 4;

    f32x4 acc[4][4] = {};
    constexpr int NT = K1P / 32;   // 10 (even)

    const unsigned short* pa[4];
    const unsigned short* pb[4];
#pragma unroll
    for (int t = 0; t < 4; ++t) {
        int r = m0 + wm * 64 + t * 16 + fr; if (r >= N_NODES) r = N_NODES - 1;
        pa[t] = A + (size_t)r * K1P + fq * 8;
        int c = n0 + wn * 64 + t * 16 + fr;
        pb[t] = Bt + (size_t)c * K1P + fq * 8;
    }

    f16x8 ca[4], cb[4], na[4], nb[4];
#pragma unroll
    for (int t = 0; t < 4; ++t) { ca[t] = *(const f16x8*)pa[t]; cb[t] = *(const f16x8*)pb[t]; }

    for (int kt = 0; kt < NT; kt += 2) {
        // even phase: prefetch kt+1, compute kt from ca/cb
        {
            const int ko = (kt + 1) * 32;
#pragma unroll
            for (int t = 0; t < 4; ++t) { na[t] = *(const f16x8*)(pa[t] + ko); nb[t] = *(const f16x8*)(pb[t] + ko); }
        }
#pragma unroll
        for (int mt = 0; mt < 4; ++mt)
#pragma unroll
            for (int nt = 0; nt < 4; ++nt)
                acc[mt][nt] = __builtin_amdgcn_mfma_f32_16x16x32_f16(ca[mt], cb[nt], acc[mt][nt], 0, 0, 0);
        // odd phase: prefetch kt+2, compute kt+1 from na/nb
        if (kt + 2 < NT) {
            const int ko = (kt + 2) * 32;
#pragma unroll
            for (int t = 0; t < 4; ++t) { ca[t] = *(const f16x8*)(pa[t] + ko); cb[t] = *(const f16x8*)(pb[t] + ko); }
        }
#pragma unroll
        for (int mt = 0; mt < 4; ++mt)
#pragma unroll
            for (int nt = 0; nt < 4; ++nt)
                acc[mt][nt] = __builtin_amdgcn_mfma_f32_16x16x32_f16(na[mt], nb[nt], acc[mt][nt], 0, 0, 0);
    }

    // epilogue
    float bv[4];
#pragma unroll
    for (int nt = 0; nt < 4; ++nt) {
        int col = n0 + wn * 64 + nt * 16 + fr;
        bv[nt] = (col < HDIM2) ? bias[col] : 0.f;
    }
    if (tid < 128) { csum[tid] = 0.f; cssq[tid] = 0.f; }
    __syncthreads();

    float colS[4] = {0.f, 0.f, 0.f, 0.f};
    float colQ[4] = {0.f, 0.f, 0.f, 0.f};
#pragma unroll
    for (int mt = 0; mt < 4; ++mt) {
#pragma unroll
        for (int r = 0; r < 4; ++r) {
            int row = m0 + wm * 64 + mt * 16 + fq * 4 + r;
            bool rok = row < N_NODES;
#pragma unroll
            for (int nt = 0; nt < 4; ++nt) {
                int col = n0 + wn * 64 + nt * 16 + fr;
                if (rok && col < HDIM2) {
                    float v = acc[mt][nt][r] + bv[nt];
                    Ch[(size_t)row * N1P + col] = f2h(v);
                    colS[nt] += v;
                    colQ[nt] += v * v;
                }
            }
        }
    }
#pragma unroll
    for (int nt = 0; nt < 4; ++nt) {
        int c = wn * 64 + nt * 16 + fr;
        atomicAdd(&csum[c], colS[nt]);
        atomicAdd(&cssq[c], colQ[nt]);
    }
    __syncthreads();
    if (tid < 128) {
        int col = n0 + tid;
        if (col < HDIM2) {
            atomicAdd(&gsum[col], csum[tid]);
            atomicAdd(&gssq[col], cssq[tid]);
        }
    }
}

// ---------- GEMM2: barrier-free per-wave direct-load; bn1+relu in-register on A ----------
__global__ __launch_bounds__(256, 2) void k_mfma2(const unsigned short* __restrict__ z1,
                                                  const unsigned short* __restrict__ Bt,
                                                  const float* __restrict__ bias,
                                                  const unsigned short* __restrict__ scaleAh,
                                                  const unsigned short* __restrict__ shiftAh,
                                                  unsigned short* __restrict__ Ch,
                                                  float* __restrict__ gsum,
                                                  float* __restrict__ gssq) {
    __shared__ float csum[128], cssq[128];

    const int tid = threadIdx.x;
    const int lane = tid & 63, wid = tid >> 6;
    const int wm = wid >> 1, wn = wid & 1;
    const int wgid = xcd_swz(blockIdx.x, NWG2);
    const int n0 = (wgid % 3) * 128, m0 = (wgid / 3) * 128;
    const int fr = lane & 15, fq = lane >> 4;

    f32x4 acc[4][4] = {};
    constexpr int NT = N1P / 32;   // 20 (even)

    const unsigned short* pa[4];
    const unsigned short* pb[4];
#pragma unroll
    for (int t = 0; t < 4; ++t) {
        int r = m0 + wm * 64 + t * 16 + fr; if (r >= N_NODES) r = N_NODES - 1;
        pa[t] = z1 + (size_t)r * N1P + fq * 8;
        int c = n0 + wn * 64 + t * 16 + fr;
        pb[t] = Bt + (size_t)c * N1P + fq * 8;
    }

    auto xform = [&](f16x8 z, int kc) -> f16x8 {
        f16x8 sa = *(const f16x8*)&scaleAh[kc];
        f16x8 sb = *(const f16x8*)&shiftAh[kc];
        f16x8 r;
#pragma unroll
        for (int j = 0; j < 8; ++j) {
            _Float16 v = z[j] * sa[j] + sb[j];
            r[j] = (v > (_Float16)0) ? v : (_Float16)0;
        }
        return r;
    };

    f16x8 ca[4], cb[4], na[4], nb[4];
#pragma unroll
    for (int t = 0; t < 4; ++t) { ca[t] = *(const f16x8*)pa[t]; cb[t] = *(const f16x8*)pb[t]; }

    for (int kt = 0; kt < NT; kt += 2) {
        // even phase
        {
            const int ko = (kt + 1) * 32;
#pragma unroll
            for (int t = 0; t < 4; ++t) { na[t] = *(const f16x8*)(pa[t] + ko); nb[t] = *(const f16x8*)(pb[t] + ko); }
        }
        {
            const int kc = kt * 32 + fq * 8;
            f16x8 af[4];
#pragma unroll
            for (int t = 0; t < 4; ++t) af[t] = xform(ca[t], kc);
#pragma unroll
            for (int mt = 0; mt < 4; ++mt)
#pragma unroll
                for (int nt = 0; nt < 4; ++nt)
                    acc[mt][nt] = __builtin_amdgcn_mfma_f32_16x16x32_f16(af[mt], cb[nt], acc[mt][nt], 0, 0, 0);
        }
        // odd phase
        if (kt + 2 < NT) {
            const int ko = (kt + 2) * 32;
#pragma unroll
            for (int t = 0; t < 4; ++t) { ca[t] = *(const f16x8*)(pa[t] + ko); cb[t] = *(const f16x8*)(pb[t] + ko); }
        }
        {
            const int kc = (kt + 1) * 32 + fq * 8;
            f16x8 af[4];
#pragma unroll
            for (int t = 0; t < 4; ++t) af[t] = xform(na[t], kc);
#pragma unroll
            for (int mt = 0; mt < 4; ++mt)
#pragma unroll
                for (int nt = 0; nt < 4; ++nt)
                    acc[mt][nt] = __builtin_amdgcn_mfma_f32_16x16x32_f16(af[mt], nb[nt], acc[mt][nt], 0, 0, 0);
        }
    }

    // epilogue (NC=300, stride K1P; pad cols never read -> not written)
    float bv[4];
#pragma unroll
    for (int nt = 0; nt < 4; ++nt) {
        int col = n0 + wn * 64 + nt * 16 + fr;
        bv[nt] = (col < HDIM) ? bias[col] : 0.f;
    }
    if (tid < 128) { csum[tid] = 0.f; cssq[tid] = 0.f; }
    __syncthreads();

    float colS[4] = {0.f, 0.f, 0.f, 0.f};
    float colQ[4] = {0.f, 0.f, 0.f, 0.f};
#pragma unroll
    for (int mt = 0; mt < 4; ++mt) {
#pragma unroll
        for (int r = 0; r < 4; ++r) {
            int row = m0 + wm * 64 + mt * 16 + fq * 4 + r;
            bool rok = row < N_NODES;
#pragma unroll
            for (int nt = 0; nt < 4; ++nt) {
                int col = n0 + wn * 64 + nt * 16 + fr;
                if (rok && col < HDIM) {
                    float v = acc[mt][nt][r] + bv[nt];
                    Ch[(size_t)row * K1P + col] = f2h(v);
                    colS[nt] += v;
                    colQ[nt] += v * v;
                }
            }
        }
    }
#pragma unroll
    for (int nt = 0; nt < 4; ++nt) {
        int c = wn * 64 + nt * 16 + fr;
        atomicAdd(&csum[c], colS[nt]);
        atomicAdd(&cssq[c], colQ[nt]);
    }
    __syncthreads();
    if (tid < 128) {
        int col = n0 + tid;
        if (col < HDIM) {
            atomicAdd(&gsum[col], csum[tid]);
            atomicAdd(&gssq[col], cssq[tid]);
        }
    }
}

// ---------- BN finalize (+ optional f16 scale/shift); zero other stats ----------
__global__ void k_fin(const float* __restrict__ gsum, const float* __restrict__ gssq,
                      const float* __restrict__ gamma, const float* __restrict__ beta,
                      int C, int CPAD, float* __restrict__ scale, float* __restrict__ shift,
                      unsigned short* scaleh, unsigned short* shifth,
                      float* zs, float* zq, int CZ) {
    int i = blockIdx.x * blockDim.x + threadIdx.x;
    if (i < CPAD) {
        float sc = 0.f, sh = 0.f;
        if (i < C) {
            float m = gsum[i] * (1.f / (float)N_NODES);
            float v = gssq[i] * (1.f / (float)N_NODES) - m * m;
            float rs = rsqrtf(v + 1e-5f);
            sc = rs * gamma[i];
            sh = beta[i] - m * sc;
        }
        scale[i] = sc;
        shift[i] = sh;
        if (scaleh) { scaleh[i] = f2h(sc); shifth[i] = f2h(sh); }
    }
    if (i < CZ) { zs[i] = 0.f; zq[i] = 0.f; }
}

// ---------- final BN: z2 (f16) -> out_h f32 (no relu) ----------
__global__ void k_normf(const unsigned short* __restrict__ z2,
                        const float* __restrict__ scale, const float* __restrict__ shift,
                        float* __restrict__ out_h) {
    int idx = blockIdx.x * blockDim.x + threadIdx.x;
    if (idx >= N_NODES * (K1P / 4)) return;
    int row = idx / (K1P / 4);
    int c = (idx % (K1P / 4)) * 4;
    if (c >= HDIM) return;
    const unsigned short* zr = z2 + (size_t)row * K1P + c;
    float4 o;
    o.x = h2f(zr[0]) * scale[c + 0] + shift[c + 0];
    o.y = h2f(zr[1]) * scale[c + 1] + shift[c + 1];
    o.z = h2f(zr[2]) * scale[c + 2] + shift[c + 2];
    o.w = h2f(zr[3]) * scale[c + 3] + shift[c + 3];
    *(float4*)(out_h + (size_t)row * HDIM + c) = o;
}

// ---------- global add pool ----------
__global__ __launch_bounds__(128) void k_pool(const float* __restrict__ hfin,
                                              const int* __restrict__ batch,
                                              float* __restrict__ xpool) {
    int g = blockIdx.x;
    int t = threadIdx.x;
    int start = lower_bound_i(batch, N_NODES, g);
    int end   = lower_bound_i(batch, N_NODES, g + 1);
    int cols[3] = { t, t + 128, t + 256 };
    float acc[3] = {0.f, 0.f, 0.f};
    for (int n = start; n < end; ++n) {
        const float* hr = hfin + (size_t)n * HDIM;
#pragma unroll
        for (int q = 0; q < 3; ++q)
            if (cols[q] < HDIM) acc[q] += hr[cols[q]];
    }
#pragma unroll
    for (int q = 0; q < 3; ++q)
        if (cols[q] < HDIM) xpool[(size_t)g * HDIM + cols[q]] = acc[q];
}

extern "C" void kernel_launch(void* const* d_in, const int* in_sizes, int n_in,
                              void* d_out, int out_size, void* d_ws, size_t ws_size,
                              hipStream_t stream) {
    const int*   batch    = (const int*)d_in[0];
    const int*   x        = (const int*)d_in[1];
    const int*   eidx     = (const int*)d_in[2];     // [2][E]
    const int*   eattr    = (const int*)d_in[3];     // [E][3]
    const float* atom_emb = (const float*)d_in[4];
    const float* bond_emb = (const float*)d_in[5];
    const float* W1 = (const float*)d_in[6];
    const float* b1 = (const float*)d_in[7];
    const float* g1 = (const float*)d_in[8];
    const float* be1 = (const float*)d_in[9];
    const float* W2 = (const float*)d_in[10];
    const float* b2 = (const float*)d_in[11];
    const float* g2 = (const float*)d_in[12];
    const float* be2 = (const float*)d_in[13];

    const int* src = eidx;
    const int* dst = eidx + N_EDGES;

    float* out_h    = (float*)d_out;                           // [N][300]
    float* out_pool = (float*)d_out + (size_t)N_NODES * HDIM;  // [G][300]

    char* ws = (char*)d_ws;
    size_t off = 0;
    auto alloc = [&](size_t bytes) -> void* {
        void* p = ws + off;
        off += (bytes + 255) & ~(size_t)255;
        return p;
    };
    unsigned short* hf    = (unsigned short*)alloc((size_t)N_NODES * K1P * 2);      // f16 [N][320]
    unsigned short* zin   = (unsigned short*)alloc((size_t)N_NODES * K1P * 2);      // f16 [N][320]
    unsigned short* z1    = (unsigned short*)alloc((size_t)N_NODES * N1P * 2);      // f16 [N][640]
    unsigned short* z2    = (unsigned short*)alloc((size_t)N_NODES * K1P * 2);      // f16 [N][320]
    unsigned short* W1t   = (unsigned short*)alloc((size_t)NLAYER * N1P * K1P * 2); // [5][640][320]
    unsigned short* W2t   = (unsigned short*)alloc((size_t)NLAYER * N2P * N1P * 2); // [5][384][640]
    unsigned short* ecomb = (unsigned short*)alloc((size_t)NCOMBO * HDIM * 2);      // f16 [4096][300]
    int* rowptr  = (int*)alloc((N_NODES + 1) * sizeof(int));
    int* deg     = (int*)alloc(N_NODES * sizeof(int));
    int* fill    = (int*)alloc(N_NODES * sizeof(int));
    int* part    = (int*)alloc(N_NODES * sizeof(int));
    int* psum    = (int*)alloc(64 * sizeof(int));
    int2* csr_rec = (int2*)alloc((size_t)N_EDGES * sizeof(int2));
    float* s1     = (float*)alloc(N1P * sizeof(float));
    float* q1     = (float*)alloc(N1P * sizeof(float));
    float* scale1 = (float*)alloc(N1P * sizeof(float));
    float* shift1 = (float*)alloc(N1P * sizeof(float));
    unsigned short* scale1h = (unsigned short*)alloc(N1P * sizeof(short));
    unsigned short* shift1h = (unsigned short*)alloc(N1P * sizeof(short));
    float* s2     = (float*)alloc(K1P * sizeof(float));
    float* q2     = (float*)alloc(K1P * sizeof(float));
    float* scale2 = (float*)alloc(K1P * sizeof(float));
    float* shift2 = (float*)alloc(K1P * sizeof(float));

    // setup
    k_init<<<(N_NODES + 255) / 256, 256, 0, stream>>>(deg, fill, s1, q1, s2, q2);
    k_atom<<<(N_NODES * K1P + 255) / 256, 256, 0, stream>>>(x, atom_emb, hf);
    k_ecomb<<<(NCOMBO * HDIM + 255) / 256, 256, 0, stream>>>(bond_emb, ecomb);
    k_deg<<<(N_EDGES + 255) / 256, 256, 0, stream>>>(dst, deg);
    k_scan1<<<NSCAN, SCAN_BLK, 0, stream>>>(deg, part, psum);
    k_scan2<<<1, 64, 0, stream>>>(psum);
    k_scan3<<<(N_NODES + 255) / 256, 256, 0, stream>>>(part, psum, rowptr);
    k_fill<<<(N_EDGES + 255) / 256, 256, 0, stream>>>(src, dst, eattr, rowptr,
                                                      fill, csr_rec);
    {
        int tot1 = NLAYER * N1P * K1P;
        k_wconv<<<(tot1 + 255) / 256, 256, 0, stream>>>(W1, W1t, HDIM, HDIM2, K1P, N1P);
        int tot2 = NLAYER * N2P * N1P;
        k_wconv<<<(tot2 + 255) / 256, 256, 0, stream>>>(W2, W2t, HDIM2, HDIM, N1P, N2P);
    }

    int msg_grid = (N_NODES + 3) / 4;
    for (int l = 0; l < NLAYER; ++l) {
        if (l == 0) {
            k_msg<false><<<msg_grid, 256, 0, stream>>>(hf, nullptr, nullptr,
                                                       rowptr, csr_rec, ecomb, zin);
        } else {
            k_msg<true><<<msg_grid, 256, 0, stream>>>(z2, scale2, shift2,
                                                      rowptr, csr_rec, ecomb, zin);
        }

        k_mfma1<<<NWG1, 256, 0, stream>>>(
            zin, W1t + (size_t)l * N1P * K1P, b1 + (size_t)l * HDIM2, z1, s1, q1);

        k_fin<<<3, 256, 0, stream>>>(s1, q1, g1 + (size_t)l * HDIM2, be1 + (size_t)l * HDIM2,
                                     HDIM2, N1P, scale1, shift1, scale1h, shift1h,
                                     s2, q2, K1P);

        k_mfma2<<<NWG2, 256, 0, stream>>>(
            z1, W2t + (size_t)l * N2P * N1P, b2 + (size_t)l * HDIM,
            scale1h, shift1h, z2, s2, q2);

        k_fin<<<3, 256, 0, stream>>>(s2, q2, g2 + (size_t)l * HDIM, be2 + (size_t)l * HDIM,
                                     HDIM, K1P, scale2, shift2, nullptr, nullptr,
                                     s1, q1, N1P);
    }

    k_normf<<<(N_NODES * (K1P / 4) + 255) / 256, 256, 0, stream>>>(
        z2, scale2, shift2, out_h);

    k_pool<<<N_GRAPHS, 128, 0, stream>>>(out_h, batch, out_pool);
}

// Round 16
// 1271.382 us; speedup vs baseline: 1.3433x; 1.3433x over previous
//
#include <hip/hip_runtime.h>

#define N_NODES 50000
#define N_EDGES 200000
#define N_GRAPHS 2048
#define HDIM 300
#define HDIM2 600
#define NLAYER 5
// padded dims for MFMA
#define K1P 320     // GEMM1 K (300 -> 320), h/zin/z2 storage stride
#define N1P 640     // GEMM1 N (600 -> 640), also GEMM2 K
#define N2P 384     // W2t row allocation (rows 300..383 zero)

#define MT64 ((N_NODES + 63) / 64)    // 782 m-tiles (64 rows)
#define NWG1 (10 * MT64)              // 7820 (640/64 n-tiles)
#define NWG2 (5 * MT64)               // 3910 (320/64 n-tiles)

#define NCOMBO 4096                   // 16^3 bond-attr combos

#define SCAN_BLK 1024
#define NSCAN ((N_NODES + SCAN_BLK - 1) / SCAN_BLK)   // 49

typedef __attribute__((ext_vector_type(8))) _Float16 f16x8;
typedef __attribute__((ext_vector_type(8))) unsigned short ushort8;
typedef __attribute__((ext_vector_type(4))) float f32x4;

__device__ __forceinline__ unsigned short f2h(float f) {
    _Float16 h = (_Float16)f;                      // RNE
    return __builtin_bit_cast(unsigned short, h);
}
__device__ __forceinline__ float h2f(unsigned short u) {
    _Float16 h = __builtin_bit_cast(_Float16, u);
    return (float)h;
}

__device__ __forceinline__ int lower_bound_i(const int* a, int n, int key) {
    int lo = 0, hi = n;
    while (lo < hi) { int mid = (lo + hi) >> 1; if (a[mid] < key) lo = mid + 1; else hi = mid; }
    return lo;
}

// bijective XCD chunking (m204)
__device__ __forceinline__ int xcd_swz(int orig, int nwg) {
    int q = nwg >> 3, r = nwg & 7;
    int xcd = orig & 7;
    int base = (xcd < r) ? xcd * (q + 1) : r * (q + 1) + (xcd - r) * q;
    return base + (orig >> 3);
}

// ---------- init ----------
__global__ void k_init(int* deg, int* fill, float* s1, float* q1, float* s2, float* q2) {
    int i = blockIdx.x * blockDim.x + threadIdx.x;
    if (i < N_NODES) { deg[i] = 0; fill[i] = 0; }
    if (i < N1P)     { s1[i] = 0.f; q1[i] = 0.f; }
    if (i < K1P)     { s2[i] = 0.f; q2[i] = 0.f; }
}

// ---------- atom encoder ----------
__global__ void k_atom(const int* __restrict__ x, const float* __restrict__ atom_emb,
                       unsigned short* __restrict__ hf) {
    int idx = blockIdx.x * blockDim.x + threadIdx.x;
    if (idx >= N_NODES * K1P) return;
    int n = idx / K1P;
    int c = idx - n * K1P;
    if (c >= HDIM) { hf[idx] = 0; return; }
    const int* xr = x + n * 9;
    float acc = 0.f;
#pragma unroll
    for (int f = 0; f < 9; ++f) {
        int row = xr[f] + f * 128;
        acc += atom_emb[(size_t)row * HDIM + c];
    }
    hf[idx] = f2h(acc);
}

// ---------- bond combo table ----------
__global__ void k_ecomb(const float* __restrict__ bond_emb, unsigned short* __restrict__ ecomb) {
    int t = blockIdx.x * blockDim.x + threadIdx.x;
    if (t >= NCOMBO * HDIM) return;
    int idx = t / HDIM, c = t - idx * HDIM;
    int a0 = idx & 15, a1 = (idx >> 4) & 15, a2 = idx >> 8;
    float v = bond_emb[(size_t)a0 * HDIM + c]
            + bond_emb[(size_t)(16 + a1) * HDIM + c]
            + bond_emb[(size_t)(32 + a2) * HDIM + c];
    ecomb[t] = f2h(v);
}

// ---------- CSR build over dst ----------
__global__ void k_deg(const int* __restrict__ dst, int* deg) {
    int j = blockIdx.x * blockDim.x + threadIdx.x;
    if (j < N_EDGES) atomicAdd(&deg[dst[j]], 1);
}

__global__ void k_scan1(const int* __restrict__ deg, int* __restrict__ part,
                        int* __restrict__ psum) {
    __shared__ int buf[SCAN_BLK];
    int b = blockIdx.x, tid = threadIdx.x;
    int i = b * SCAN_BLK + tid;
    int v = (i < N_NODES) ? deg[i] : 0;
    buf[tid] = v;
    __syncthreads();
    for (int off = 1; off < SCAN_BLK; off <<= 1) {
        int t = (tid >= off) ? buf[tid - off] : 0;
        __syncthreads();
        buf[tid] += t;
        __syncthreads();
    }
    if (i < N_NODES) part[i] = buf[tid];
    if (tid == SCAN_BLK - 1) psum[b] = buf[tid];
}

__global__ void k_scan2(int* __restrict__ psum) {
    __shared__ int buf[64];
    int tid = threadIdx.x;
    int v = (tid < NSCAN) ? psum[tid] : 0;
    buf[tid] = v;
    __syncthreads();
    for (int off = 1; off < 64; off <<= 1) {
        int t = (tid >= off) ? buf[tid - off] : 0;
        __syncthreads();
        buf[tid] += t;
        __syncthreads();
    }
    if (tid < NSCAN) psum[tid] = buf[tid] - v;
}

__global__ void k_scan3(const int* __restrict__ part, const int* __restrict__ psum,
                        int* __restrict__ rowptr) {
    int i = blockIdx.x * blockDim.x + threadIdx.x;
    if (i == 0) rowptr[0] = 0;
    if (i < N_NODES) rowptr[i + 1] = part[i] + psum[i / SCAN_BLK];
}

// fill packed CSR records: int2 {src, combo idx}
__global__ void k_fill(const int* __restrict__ src, const int* __restrict__ dst,
                       const int* __restrict__ eattr, const int* __restrict__ rowptr,
                       int* fill, int2* __restrict__ csr_rec) {
    int j = blockIdx.x * blockDim.x + threadIdx.x;
    if (j < N_EDGES) {
        int d = dst[j];
        int p = atomicAdd(&fill[d], 1);
        int pos = rowptr[d] + p;
        int combo = eattr[j * 3 + 0] | (eattr[j * 3 + 1] << 4) | (eattr[j * 3 + 2] << 8);
        csr_rec[pos] = make_int2(src[j], combo);
    }
}

// ---------- weight transpose + f16 convert ----------
__global__ void k_wconv(const float* __restrict__ W, unsigned short* __restrict__ Bt,
                        int K, int NC, int KPAD, int NPAD) {
    int idx = blockIdx.x * blockDim.x + threadIdx.x;
    int tot = NLAYER * NPAD * KPAD;
    if (idx >= tot) return;
    int l = idx / (NPAD * KPAD);
    int rem = idx - l * NPAD * KPAD;
    int n = rem / KPAD;
    int k = rem - n * KPAD;
    float v = (k < K && n < NC) ? W[((size_t)l * K + k) * NC + n] : 0.f;
    Bt[idx] = f2h(v);
}

// ---------- message passing: one node per wave, 4 waves/block ----------
template <bool BN>
__global__ __launch_bounds__(256) void k_msg(const unsigned short* __restrict__ hsrc,
                                             const float* __restrict__ sc,
                                             const float* __restrict__ sh,
                                             const int* __restrict__ rowptr,
                                             const int2* __restrict__ csr_rec,
                                             const unsigned short* __restrict__ ecomb,
                                             unsigned short* __restrict__ zin) {
    int wid = threadIdx.x >> 6, lane = threadIdx.x & 63;
    int n = blockIdx.x * 4 + wid;
    if (n >= N_NODES) return;

    float scv[5], shv[5], acc[5];
#pragma unroll
    for (int q = 0; q < 5; ++q) {
        int c = lane + 64 * q;
        scv[q] = 0.f; shv[q] = 0.f; acc[q] = 0.f;
        if (c < HDIM) {
            if (BN) { scv[q] = sc[c]; shv[q] = sh[c]; }
            float v = h2f(hsrc[(size_t)n * K1P + c]);
            if (BN) v = fmaxf(v * scv[q] + shv[q], 0.f);
            acc[q] = v;
        }
    }

    int beg = rowptr[n], end = rowptr[n + 1];
    int p = beg;
    for (; p + 2 <= end; p += 2) {
        int2 r0 = csr_rec[p];
        int2 r1 = csr_rec[p + 1];
        const unsigned short* h0 = hsrc + (size_t)r0.x * K1P;
        const unsigned short* h1 = hsrc + (size_t)r1.x * K1P;
        const unsigned short* e0 = ecomb + (size_t)r0.y * HDIM;
        const unsigned short* e1 = ecomb + (size_t)r1.y * HDIM;
#pragma unroll
        for (int q = 0; q < 5; ++q) {
            int c = lane + 64 * q;
            if (c < HDIM) {
                float v0 = h2f(h0[c]);
                float v1 = h2f(h1[c]);
                if (BN) {
                    v0 = fmaxf(v0 * scv[q] + shv[q], 0.f);
                    v1 = fmaxf(v1 * scv[q] + shv[q], 0.f);
                }
                float m0 = v0 + h2f(e0[c]);
                float m1 = v1 + h2f(e1[c]);
                acc[q] += fmaxf(m0, 0.f) + fmaxf(m1, 0.f);
            }
        }
    }
    if (p < end) {
        int2 r0 = csr_rec[p];
        const unsigned short* h0 = hsrc + (size_t)r0.x * K1P;
        const unsigned short* e0 = ecomb + (size_t)r0.y * HDIM;
#pragma unroll
        for (int q = 0; q < 5; ++q) {
            int c = lane + 64 * q;
            if (c < HDIM) {
                float v0 = h2f(h0[c]);
                if (BN) v0 = fmaxf(v0 * scv[q] + shv[q], 0.f);
                float m0 = v0 + h2f(e0[c]);
                acc[q] += fmaxf(m0, 0.f);
            }
        }
    }
    unsigned short* zr = zin + (size_t)n * K1P;
#pragma unroll
    for (int q = 0; q < 5; ++q) {
        int c = lane + 64 * q;
        if (c < HDIM) zr[c] = f2h(acc[q]);
    }
}

// ---------- GEMM1: 1-wave workgroup, 64x64 tile, gload_lds, 3-buf counted vmcnt ----------
// Per-wave pipeline, NO barriers: wait vmcnt(8) keeps next tile's 8 loads in flight.
__global__ __launch_bounds__(64) void k_mfma1(const unsigned short* __restrict__ A,
                                              const unsigned short* __restrict__ Bt,
                                              const float* __restrict__ bias,
                                              unsigned short* __restrict__ Ch,
                                              float* __restrict__ gsum,
                                              float* __restrict__ gssq) {
    __shared__ unsigned short tA[3][64 * 32];
    __shared__ unsigned short tB[3][64 * 32];

    const int lane = threadIdx.x;
    const int wgid = xcd_swz(blockIdx.x, NWG1);
    const int n0 = (wgid % 10) * 64, m0 = (wgid / 10) * 64;
    const int fr = lane & 15, fq = lane >> 4;

    f32x4 acc[4][4] = {};
    const int srow = lane >> 2;          // 0..15
    const int schk = (lane & 3) * 8;
    constexpr int NT = K1P / 32;   // 10

    auto stage = [&](int buf, int kt) {
        const int k0 = kt * 32;
#pragma unroll
        for (int i = 0; i < 4; ++i) {
            int grow = m0 + i * 16 + srow;
            if (grow >= N_NODES) grow = N_NODES - 1;
            const unsigned short* ga = A + (size_t)grow * K1P + k0 + schk;
            __builtin_amdgcn_global_load_lds((const __attribute__((address_space(1))) void*)ga,
                                             (__attribute__((address_space(3))) void*)&tA[buf][i * 512],
                                             16, 0, 0);
            int gn = n0 + i * 16 + srow;
            const unsigned short* gb = Bt + (size_t)gn * K1P + k0 + schk;
            __builtin_amdgcn_global_load_lds((const __attribute__((address_space(1))) void*)gb,
                                             (__attribute__((address_space(3))) void*)&tB[buf][i * 512],
                                             16, 0, 0);
        }
    };

    stage(0, 0);
    stage(1, 1);

    int cur = 0;
    for (int kt = 0; kt < NT; ++kt) {
        if (kt + 1 < NT) asm volatile("s_waitcnt vmcnt(8)" ::: "memory");
        else             asm volatile("s_waitcnt vmcnt(0)" ::: "memory");
        if (kt + 2 < NT) {
            int nb = cur + 2; if (nb >= 3) nb -= 3;
            stage(nb, kt + 2);
        }

        f16x8 af[4], bfr[4];
#pragma unroll
        for (int t = 0; t < 4; ++t) {
            af[t]  = *(const f16x8*)&tA[cur][(t * 16 + fr) * 32 + fq * 8];
            bfr[t] = *(const f16x8*)&tB[cur][(t * 16 + fr) * 32 + fq * 8];
        }
#pragma unroll
        for (int mt = 0; mt < 4; ++mt)
#pragma unroll
            for (int nt = 0; nt < 4; ++nt)
                acc[mt][nt] = __builtin_amdgcn_mfma_f32_16x16x32_f16(af[mt], bfr[nt], acc[mt][nt], 0, 0, 0);

        cur = (cur == 2) ? 0 : cur + 1;
    }

    // epilogue: bias, store, stats via wave shuffle reduce (no LDS, no barrier)
    float bv[4];
#pragma unroll
    for (int nt = 0; nt < 4; ++nt) {
        int col = n0 + nt * 16 + fr;
        bv[nt] = (col < HDIM2) ? bias[col] : 0.f;
    }
    float colS[4] = {0.f, 0.f, 0.f, 0.f};
    float colQ[4] = {0.f, 0.f, 0.f, 0.f};
#pragma unroll
    for (int mt = 0; mt < 4; ++mt) {
#pragma unroll
        for (int r = 0; r < 4; ++r) {
            int row = m0 + mt * 16 + fq * 4 + r;
            bool rok = row < N_NODES;
#pragma unroll
            for (int nt = 0; nt < 4; ++nt) {
                int col = n0 + nt * 16 + fr;
                if (rok && col < HDIM2) {
                    float v = acc[mt][nt][r] + bv[nt];
                    Ch[(size_t)row * N1P + col] = f2h(v);
                    colS[nt] += v;
                    colQ[nt] += v * v;
                }
            }
        }
    }
#pragma unroll
    for (int nt = 0; nt < 4; ++nt) {
        colS[nt] += __shfl_xor(colS[nt], 16);
        colS[nt] += __shfl_xor(colS[nt], 32);
        colQ[nt] += __shfl_xor(colQ[nt], 16);
        colQ[nt] += __shfl_xor(colQ[nt], 32);
    }
    if (lane < 16) {
#pragma unroll
        for (int nt = 0; nt < 4; ++nt) {
            int col = n0 + nt * 16 + fr;
            if (col < HDIM2) {
                atomicAdd(&gsum[col], colS[nt]);
                atomicAdd(&gssq[col], colQ[nt]);
            }
        }
    }
}

// ---------- GEMM2: 1-wave workgroup, 64x64 tile; bn1+relu in-register on A ----------
__global__ __launch_bounds__(64) void k_mfma2(const unsigned short* __restrict__ z1,
                                              const unsigned short* __restrict__ Bt,
                                              const float* __restrict__ bias,
                                              const unsigned short* __restrict__ scaleAh,
                                              const unsigned short* __restrict__ shiftAh,
                                              unsigned short* __restrict__ Ch,
                                              float* __restrict__ gsum,
                                              float* __restrict__ gssq) {
    __shared__ unsigned short tA[3][64 * 32];
    __shared__ unsigned short tB[3][64 * 32];

    const int lane = threadIdx.x;
    const int wgid = xcd_swz(blockIdx.x, NWG2);
    const int n0 = (wgid % 5) * 64, m0 = (wgid / 5) * 64;
    const int fr = lane & 15, fq = lane >> 4;

    f32x4 acc[4][4] = {};
    const int srow = lane >> 2;
    const int schk = (lane & 3) * 8;
    constexpr int NT = N1P / 32;   // 20

    auto stage = [&](int buf, int kt) {
        const int k0 = kt * 32;
#pragma unroll
        for (int i = 0; i < 4; ++i) {
            int grow = m0 + i * 16 + srow;
            if (grow >= N_NODES) grow = N_NODES - 1;
            const unsigned short* ga = z1 + (size_t)grow * N1P + k0 + schk;
            __builtin_amdgcn_global_load_lds((const __attribute__((address_space(1))) void*)ga,
                                             (__attribute__((address_space(3))) void*)&tA[buf][i * 512],
                                             16, 0, 0);
            int gn = n0 + i * 16 + srow;
            const unsigned short* gb = Bt + (size_t)gn * N1P + k0 + schk;
            __builtin_amdgcn_global_load_lds((const __attribute__((address_space(1))) void*)gb,
                                             (__attribute__((address_space(3))) void*)&tB[buf][i * 512],
                                             16, 0, 0);
        }
    };

    stage(0, 0);
    stage(1, 1);

    int cur = 0;
    for (int kt = 0; kt < NT; ++kt) {
        if (kt + 1 < NT) asm volatile("s_waitcnt vmcnt(8)" ::: "memory");
        else             asm volatile("s_waitcnt vmcnt(0)" ::: "memory");
        if (kt + 2 < NT) {
            int nb = cur + 2; if (nb >= 3) nb -= 3;
            stage(nb, kt + 2);
        }

        const int kc = kt * 32 + fq * 8;
        f16x8 sa = *(const f16x8*)&scaleAh[kc];
        f16x8 sb = *(const f16x8*)&shiftAh[kc];
        f16x8 af[4], bfr[4];
#pragma unroll
        for (int t = 0; t < 4; ++t) {
            f16x8 z = *(const f16x8*)&tA[cur][(t * 16 + fr) * 32 + fq * 8];
            f16x8 r;
#pragma unroll
            for (int j = 0; j < 8; ++j) {
                _Float16 v = z[j] * sa[j] + sb[j];
                r[j] = (v > (_Float16)0) ? v : (_Float16)0;
            }
            af[t] = r;
            bfr[t] = *(const f16x8*)&tB[cur][(t * 16 + fr) * 32 + fq * 8];
        }
#pragma unroll
        for (int mt = 0; mt < 4; ++mt)
#pragma unroll
            for (int nt = 0; nt < 4; ++nt)
                acc[mt][nt] = __builtin_amdgcn_mfma_f32_16x16x32_f16(af[mt], bfr[nt], acc[mt][nt], 0, 0, 0);

        cur = (cur == 2) ? 0 : cur + 1;
    }

    // epilogue (NC=300, stride K1P)
    float bv[4];
#pragma unroll
    for (int nt = 0; nt < 4; ++nt) {
        int col = n0 + nt * 16 + fr;
        bv[nt] = (col < HDIM) ? bias[col] : 0.f;
    }
    float colS[4] = {0.f, 0.f, 0.f, 0.f};
    float colQ[4] = {0.f, 0.f, 0.f, 0.f};
#pragma unroll
    for (int mt = 0; mt < 4; ++mt) {
#pragma unroll
        for (int r = 0; r < 4; ++r) {
            int row = m0 + mt * 16 + fq * 4 + r;
            bool rok = row < N_NODES;
#pragma unroll
            for (int nt = 0; nt < 4; ++nt) {
                int col = n0 + nt * 16 + fr;
                if (rok && col < HDIM) {
                    float v = acc[mt][nt][r] + bv[nt];
                    Ch[(size_t)row * K1P + col] = f2h(v);
                    colS[nt] += v;
                    colQ[nt] += v * v;
                }
            }
        }
    }
#pragma unroll
    for (int nt = 0; nt < 4; ++nt) {
        colS[nt] += __shfl_xor(colS[nt], 16);
        colS[nt] += __shfl_xor(colS[nt], 32);
        colQ[nt] += __shfl_xor(colQ[nt], 16);
        colQ[nt] += __shfl_xor(colQ[nt], 32);
    }
    if (lane < 16) {
#pragma unroll
        for (int nt = 0; nt < 4; ++nt) {
            int col = n0 + nt * 16 + fr;
            if (col < HDIM) {
                atomicAdd(&gsum[col], colS[nt]);
                atomicAdd(&gssq[col], colQ[nt]);
            }
        }
    }
}

// ---------- BN finalize (+ optional f16 scale/shift); zero other stats ----------
__global__ void k_fin(const float* __restrict__ gsum, const float* __restrict__ gssq,
                      const float* __restrict__ gamma, const float* __restrict__ beta,
                      int C, int CPAD, float* __restrict__ scale, float* __restrict__ shift,
                      unsigned short* scaleh, unsigned short* shifth,
                      float* zs, float* zq, int CZ) {
    int i = blockIdx.x * blockDim.x + threadIdx.x;
    if (i < CPAD) {
        float sc = 0.f, sh = 0.f;
        if (i < C) {
            float m = gsum[i] * (1.f / (float)N_NODES);
            float v = gssq[i] * (1.f / (float)N_NODES) - m * m;
            float rs = rsqrtf(v + 1e-5f);
            sc = rs * gamma[i];
            sh = beta[i] - m * sc;
        }
        scale[i] = sc;
        shift[i] = sh;
        if (scaleh) { scaleh[i] = f2h(sc); shifth[i] = f2h(sh); }
    }
    if (i < CZ) { zs[i] = 0.f; zq[i] = 0.f; }
}

// ---------- final BN: z2 (f16) -> out_h f32 (no relu) ----------
__global__ void k_normf(const unsigned short* __restrict__ z2,
                        const float* __restrict__ scale, const float* __restrict__ shift,
                        float* __restrict__ out_h) {
    int idx = blockIdx.x * blockDim.x + threadIdx.x;
    if (idx >= N_NODES * (K1P / 4)) return;
    int row = idx / (K1P / 4);
    int c = (idx % (K1P / 4)) * 4;
    if (c >= HDIM) return;
    const unsigned short* zr = z2 + (size_t)row * K1P + c;
    float4 o;
    o.x = h2f(zr[0]) * scale[c + 0] + shift[c + 0];
    o.y = h2f(zr[1]) * scale[c + 1] + shift[c + 1];
    o.z = h2f(zr[2]) * scale[c + 2] + shift[c + 2];
    o.w = h2f(zr[3]) * scale[c + 3] + shift[c + 3];
    *(float4*)(out_h + (size_t)row * HDIM + c) = o;
}

// ---------- global add pool ----------
__global__ __launch_bounds__(128) void k_pool(const float* __restrict__ hfin,
                                              const int* __restrict__ batch,
                                              float* __restrict__ xpool) {
    int g = blockIdx.x;
    int t = threadIdx.x;
    int start = lower_bound_i(batch, N_NODES, g);
    int end   = lower_bound_i(batch, N_NODES, g + 1);
    int cols[3] = { t, t + 128, t + 256 };
    float acc[3] = {0.f, 0.f, 0.f};
    for (int n = start; n < end; ++n) {
        const float* hr = hfin + (size_t)n * HDIM;
#pragma unroll
        for (int q = 0; q < 3; ++q)
            if (cols[q] < HDIM) acc[q] += hr[cols[q]];
    }
#pragma unroll
    for (int q = 0; q < 3; ++q)
        if (cols[q] < HDIM) xpool[(size_t)g * HDIM + cols[q]] = acc[q];
}

extern "C" void kernel_launch(void* const* d_in, const int* in_sizes, int n_in,
                              void* d_out, int out_size, void* d_ws, size_t ws_size,
                              hipStream_t stream) {
    const int*   batch    = (const int*)d_in[0];
    const int*   x        = (const int*)d_in[1];
    const int*   eidx     = (const int*)d_in[2];     // [2][E]
    const int*   eattr    = (const int*)d_in[3];     // [E][3]
    const float* atom_emb = (const float*)d_in[4];
    const float* bond_emb = (const float*)d_in[5];
    const float* W1 = (const float*)d_in[6];
    const float* b1 = (const float*)d_in[7];
    const float* g1 = (const float*)d_in[8];
    const float* be1 = (const float*)d_in[9];
    const float* W2 = (const float*)d_in[10];
    const float* b2 = (const float*)d_in[11];
    const float* g2 = (const float*)d_in[12];
    const float* be2 = (const float*)d_in[13];

    const int* src = eidx;
    const int* dst = eidx + N_EDGES;

    float* out_h    = (float*)d_out;                           // [N][300]
    float* out_pool = (float*)d_out + (size_t)N_NODES * HDIM;  // [G][300]

    char* ws = (char*)d_ws;
    size_t off = 0;
    auto alloc = [&](size_t bytes) -> void* {
        void* p = ws + off;
        off += (bytes + 255) & ~(size_t)255;
        return p;
    };
    unsigned short* hf    = (unsigned short*)alloc((size_t)N_NODES * K1P * 2);      // f16 [N][320]
    unsigned short* zin   = (unsigned short*)alloc((size_t)N_NODES * K1P * 2);      // f16 [N][320]
    unsigned short* z1    = (unsigned short*)alloc((size_t)N_NODES * N1P * 2);      // f16 [N][640]
    unsigned short* z2    = (unsigned short*)alloc((size_t)N_NODES * K1P * 2);      // f16 [N][320]
    unsigned short* W1t   = (unsigned short*)alloc((size_t)NLAYER * N1P * K1P * 2); // [5][640][320]
    unsigned short* W2t   = (unsigned short*)alloc((size_t)NLAYER * N2P * N1P * 2); // [5][384][640]
    unsigned short* ecomb = (unsigned short*)alloc((size_t)NCOMBO * HDIM * 2);      // f16 [4096][300]
    int* rowptr  = (int*)alloc((N_NODES + 1) * sizeof(int));
    int* deg     = (int*)alloc(N_NODES * sizeof(int));
    int* fill    = (int*)alloc(N_NODES * sizeof(int));
    int* part    = (int*)alloc(N_NODES * sizeof(int));
    int* psum    = (int*)alloc(64 * sizeof(int));
    int2* csr_rec = (int2*)alloc((size_t)N_EDGES * sizeof(int2));
    float* s1     = (float*)alloc(N1P * sizeof(float));
    float* q1     = (float*)alloc(N1P * sizeof(float));
    float* scale1 = (float*)alloc(N1P * sizeof(float));
    float* shift1 = (float*)alloc(N1P * sizeof(float));
    unsigned short* scale1h = (unsigned short*)alloc(N1P * sizeof(short));
    unsigned short* shift1h = (unsigned short*)alloc(N1P * sizeof(short));
    float* s2     = (float*)alloc(K1P * sizeof(float));
    float* q2     = (float*)alloc(K1P * sizeof(float));
    float* scale2 = (float*)alloc(K1P * sizeof(float));
    float* shift2 = (float*)alloc(K1P * sizeof(float));

    // setup
    k_init<<<(N_NODES + 255) / 256, 256, 0, stream>>>(deg, fill, s1, q1, s2, q2);
    k_atom<<<(N_NODES * K1P + 255) / 256, 256, 0, stream>>>(x, atom_emb, hf);
    k_ecomb<<<(NCOMBO * HDIM + 255) / 256, 256, 0, stream>>>(bond_emb, ecomb);
    k_deg<<<(N_EDGES + 255) / 256, 256, 0, stream>>>(dst, deg);
    k_scan1<<<NSCAN, SCAN_BLK, 0, stream>>>(deg, part, psum);
    k_scan2<<<1, 64, 0, stream>>>(psum);
    k_scan3<<<(N_NODES + 255) / 256, 256, 0, stream>>>(part, psum, rowptr);
    k_fill<<<(N_EDGES + 255) / 256, 256, 0, stream>>>(src, dst, eattr, rowptr,
                                                      fill, csr_rec);
    {
        int tot1 = NLAYER * N1P * K1P;
        k_wconv<<<(tot1 + 255) / 256, 256, 0, stream>>>(W1, W1t, HDIM, HDIM2, K1P, N1P);
        int tot2 = NLAYER * N2P * N1P;
        k_wconv<<<(tot2 + 255) / 256, 256, 0, stream>>>(W2, W2t, HDIM2, HDIM, N1P, N2P);
    }

    int msg_grid = (N_NODES + 3) / 4;
    for (int l = 0; l < NLAYER; ++l) {
        if (l == 0) {
            k_msg<false><<<msg_grid, 256, 0, stream>>>(hf, nullptr, nullptr,
                                                       rowptr, csr_rec, ecomb, zin);
        } else {
            k_msg<true><<<msg_grid, 256, 0, stream>>>(z2, scale2, shift2,
                                                      rowptr, csr_rec, ecomb, zin);
        }

        k_mfma1<<<NWG1, 64, 0, stream>>>(
            zin, W1t + (size_t)l * N1P * K1P, b1 + (size_t)l * HDIM2, z1, s1, q1);

        k_fin<<<3, 256, 0, stream>>>(s1, q1, g1 + (size_t)l * HDIM2, be1 + (size_t)l * HDIM2,
                                     HDIM2, N1P, scale1, shift1, scale1h, shift1h,
                                     s2, q2, K1P);

        k_mfma2<<<NWG2, 64, 0, stream>>>(
            z1, W2t + (size_t)l * N2P * N1P, b2 + (size_t)l * HDIM,
            scale1h, shift1h, z2, s2, q2);

        k_fin<<<3, 256, 0, stream>>>(s2, q2, g2 + (size_t)l * HDIM, be2 + (size_t)l * HDIM,
                                     HDIM, K1P, scale2, shift2, nullptr, nullptr,
                                     s1, q1, N1P);
    }

    k_normf<<<(N_NODES * (K1P / 4) + 255) / 256, 256, 0, stream>>>(
        z2, scale2, shift2, out_h);

    k_pool<<<N_GRAPHS, 128, 0, stream>>>(out_h, batch, out_pool);
}

// Round 17
// 1039.400 us; speedup vs baseline: 1.6431x; 1.2232x over previous
//
#include <hip/hip_runtime.h>

#define N_NODES 50000
#define N_EDGES 200000
#define N_GRAPHS 2048
#define HDIM 300
#define HDIM2 600
#define NLAYER 5
// padded dims for MFMA
#define K1P 320     // GEMM1 K (300 -> 320), h/zin/z2 storage stride
#define N1P 640     // GEMM1 N (600 -> 640), also GEMM2 K
#define N2P 384     // W2t row allocation (rows 300..383 zero)

#define MT1 ((N_NODES + 127) / 128)   // 391 m-tiles
#define NWG1 (5 * MT1)                // 1955
#define NWG2 (3 * MT1)                // 1173

#define NCOMBO 4096                   // 16^3 bond-attr combos

#define SCAN_BLK 1024
#define NSCAN ((N_NODES + SCAN_BLK - 1) / SCAN_BLK)   // 49

typedef __attribute__((ext_vector_type(8))) _Float16 f16x8;
typedef __attribute__((ext_vector_type(8))) unsigned short ushort8;
typedef __attribute__((ext_vector_type(4))) float f32x4;

__device__ __forceinline__ unsigned short f2h(float f) {
    _Float16 h = (_Float16)f;                      // RNE
    return __builtin_bit_cast(unsigned short, h);
}
__device__ __forceinline__ float h2f(unsigned short u) {
    _Float16 h = __builtin_bit_cast(_Float16, u);
    return (float)h;
}

__device__ __forceinline__ int lower_bound_i(const int* a, int n, int key) {
    int lo = 0, hi = n;
    while (lo < hi) { int mid = (lo + hi) >> 1; if (a[mid] < key) lo = mid + 1; else hi = mid; }
    return lo;
}

// bijective XCD chunking (m204)
__device__ __forceinline__ int xcd_swz(int orig, int nwg) {
    int q = nwg >> 3, r = nwg & 7;
    int xcd = orig & 7;
    int base = (xcd < r) ? xcd * (q + 1) : r * (q + 1) + (xcd - r) * q;
    return base + (orig >> 3);
}

// ---------- init ----------
__global__ void k_init(int* deg, int* fill, float* s1, float* q1, float* s2, float* q2) {
    int i = blockIdx.x * blockDim.x + threadIdx.x;
    if (i < N_NODES) { deg[i] = 0; fill[i] = 0; }
    if (i < N1P)     { s1[i] = 0.f; q1[i] = 0.f; }
    if (i < K1P)     { s2[i] = 0.f; q2[i] = 0.f; }
}

// ---------- atom encoder ----------
__global__ void k_atom(const int* __restrict__ x, const float* __restrict__ atom_emb,
                       unsigned short* __restrict__ hf) {
    int idx = blockIdx.x * blockDim.x + threadIdx.x;
    if (idx >= N_NODES * K1P) return;
    int n = idx / K1P;
    int c = idx - n * K1P;
    if (c >= HDIM) { hf[idx] = 0; return; }
    const int* xr = x + n * 9;
    float acc = 0.f;
#pragma unroll
    for (int f = 0; f < 9; ++f) {
        int row = xr[f] + f * 128;
        acc += atom_emb[(size_t)row * HDIM + c];
    }
    hf[idx] = f2h(acc);
}

// ---------- bond combo table ----------
__global__ void k_ecomb(const float* __restrict__ bond_emb, unsigned short* __restrict__ ecomb) {
    int t = blockIdx.x * blockDim.x + threadIdx.x;
    if (t >= NCOMBO * HDIM) return;
    int idx = t / HDIM, c = t - idx * HDIM;
    int a0 = idx & 15, a1 = (idx >> 4) & 15, a2 = idx >> 8;
    float v = bond_emb[(size_t)a0 * HDIM + c]
            + bond_emb[(size_t)(16 + a1) * HDIM + c]
            + bond_emb[(size_t)(32 + a2) * HDIM + c];
    ecomb[t] = f2h(v);
}

// ---------- CSR build over dst ----------
__global__ void k_deg(const int* __restrict__ dst, int* deg) {
    int j = blockIdx.x * blockDim.x + threadIdx.x;
    if (j < N_EDGES) atomicAdd(&deg[dst[j]], 1);
}

__global__ void k_scan1(const int* __restrict__ deg, int* __restrict__ part,
                        int* __restrict__ psum) {
    __shared__ int buf[SCAN_BLK];
    int b = blockIdx.x, tid = threadIdx.x;
    int i = b * SCAN_BLK + tid;
    int v = (i < N_NODES) ? deg[i] : 0;
    buf[tid] = v;
    __syncthreads();
    for (int off = 1; off < SCAN_BLK; off <<= 1) {
        int t = (tid >= off) ? buf[tid - off] : 0;
        __syncthreads();
        buf[tid] += t;
        __syncthreads();
    }
    if (i < N_NODES) part[i] = buf[tid];
    if (tid == SCAN_BLK - 1) psum[b] = buf[tid];
}

__global__ void k_scan2(int* __restrict__ psum) {
    __shared__ int buf[64];
    int tid = threadIdx.x;
    int v = (tid < NSCAN) ? psum[tid] : 0;
    buf[tid] = v;
    __syncthreads();
    for (int off = 1; off < 64; off <<= 1) {
        int t = (tid >= off) ? buf[tid - off] : 0;
        __syncthreads();
        buf[tid] += t;
        __syncthreads();
    }
    if (tid < NSCAN) psum[tid] = buf[tid] - v;
}

__global__ void k_scan3(const int* __restrict__ part, const int* __restrict__ psum,
                        int* __restrict__ rowptr) {
    int i = blockIdx.x * blockDim.x + threadIdx.x;
    if (i == 0) rowptr[0] = 0;
    if (i < N_NODES) rowptr[i + 1] = part[i] + psum[i / SCAN_BLK];
}

// fill packed CSR records: int2 {src, combo idx}
__global__ void k_fill(const int* __restrict__ src, const int* __restrict__ dst,
                       const int* __restrict__ eattr, const int* __restrict__ rowptr,
                       int* fill, int2* __restrict__ csr_rec) {
    int j = blockIdx.x * blockDim.x + threadIdx.x;
    if (j < N_EDGES) {
        int d = dst[j];
        int p = atomicAdd(&fill[d], 1);
        int pos = rowptr[d] + p;
        int combo = eattr[j * 3 + 0] | (eattr[j * 3 + 1] << 4) | (eattr[j * 3 + 2] << 8);
        csr_rec[pos] = make_int2(src[j], combo);
    }
}

// ---------- weight transpose + f16 convert ----------
__global__ void k_wconv(const float* __restrict__ W, unsigned short* __restrict__ Bt,
                        int K, int NC, int KPAD, int NPAD) {
    int idx = blockIdx.x * blockDim.x + threadIdx.x;
    int tot = NLAYER * NPAD * KPAD;
    if (idx >= tot) return;
    int l = idx / (NPAD * KPAD);
    int rem = idx - l * NPAD * KPAD;
    int n = rem / KPAD;
    int k = rem - n * KPAD;
    float v = (k < K && n < NC) ? W[((size_t)l * K + k) * NC + n] : 0.f;
    Bt[idx] = f2h(v);
}

// ---------- message passing: one node per wave, 4 waves/block ----------
template <bool BN>
__global__ __launch_bounds__(256) void k_msg(const unsigned short* __restrict__ hsrc,
                                             const float* __restrict__ sc,
                                             const float* __restrict__ sh,
                                             const int* __restrict__ rowptr,
                                             const int2* __restrict__ csr_rec,
                                             const unsigned short* __restrict__ ecomb,
                                             unsigned short* __restrict__ zin) {
    int wid = threadIdx.x >> 6, lane = threadIdx.x & 63;
    int n = blockIdx.x * 4 + wid;
    if (n >= N_NODES) return;

    float scv[5], shv[5], acc[5];
#pragma unroll
    for (int q = 0; q < 5; ++q) {
        int c = lane + 64 * q;
        scv[q] = 0.f; shv[q] = 0.f; acc[q] = 0.f;
        if (c < HDIM) {
            if (BN) { scv[q] = sc[c]; shv[q] = sh[c]; }
            float v = h2f(hsrc[(size_t)n * K1P + c]);
            if (BN) v = fmaxf(v * scv[q] + shv[q], 0.f);
            acc[q] = v;
        }
    }

    int beg = rowptr[n], end = rowptr[n + 1];
    int p = beg;
    for (; p + 2 <= end; p += 2) {
        int2 r0 = csr_rec[p];
        int2 r1 = csr_rec[p + 1];
        const unsigned short* h0 = hsrc + (size_t)r0.x * K1P;
        const unsigned short* h1 = hsrc + (size_t)r1.x * K1P;
        const unsigned short* e0 = ecomb + (size_t)r0.y * HDIM;
        const unsigned short* e1 = ecomb + (size_t)r1.y * HDIM;
#pragma unroll
        for (int q = 0; q < 5; ++q) {
            int c = lane + 64 * q;
            if (c < HDIM) {
                float v0 = h2f(h0[c]);
                float v1 = h2f(h1[c]);
                if (BN) {
                    v0 = fmaxf(v0 * scv[q] + shv[q], 0.f);
                    v1 = fmaxf(v1 * scv[q] + shv[q], 0.f);
                }
                float m0 = v0 + h2f(e0[c]);
                float m1 = v1 + h2f(e1[c]);
                acc[q] += fmaxf(m0, 0.f) + fmaxf(m1, 0.f);
            }
        }
    }
    if (p < end) {
        int2 r0 = csr_rec[p];
        const unsigned short* h0 = hsrc + (size_t)r0.x * K1P;
        const unsigned short* e0 = ecomb + (size_t)r0.y * HDIM;
#pragma unroll
        for (int q = 0; q < 5; ++q) {
            int c = lane + 64 * q;
            if (c < HDIM) {
                float v0 = h2f(h0[c]);
                if (BN) v0 = fmaxf(v0 * scv[q] + shv[q], 0.f);
                float m0 = v0 + h2f(e0[c]);
                acc[q] += fmaxf(m0, 0.f);
            }
        }
    }
    unsigned short* zr = zin + (size_t)n * K1P;
#pragma unroll
    for (int q = 0; q < 5; ++q) {
        int c = lane + 64 * q;
        if (c < HDIM) zr[c] = f2h(acc[q]);
    }
}

// ---------- GEMM1: 128x128 tile, 4 waves, BK=32, gload_lds, 2-phase (best-known r14) ----------
__global__ __launch_bounds__(256, 4) void k_mfma1(const unsigned short* __restrict__ A,
                                                  const unsigned short* __restrict__ Bt,
                                                  const float* __restrict__ bias,
                                                  unsigned short* __restrict__ Ch,
                                                  float* __restrict__ gsum,
                                                  float* __restrict__ gssq) {
    __shared__ unsigned short tA[2][128 * 32];
    __shared__ unsigned short tB[2][128 * 32];
    __shared__ float csum[128], cssq[128];

    const int tid = threadIdx.x;
    const int lane = tid & 63, wid = tid >> 6;
    const int wm = wid >> 1, wn = wid & 1;
    const int wgid = xcd_swz(blockIdx.x, NWG1);
    const int n0 = (wgid % 5) * 128, m0 = (wgid / 5) * 128;
    const int fr = lane & 15, fq = lane >> 4;

    f32x4 acc[4][4] = {};
    const int arow = lane >> 2;
    const int achk = (lane & 3) * 8;
    const int sk = achk ^ ((arow & 3) << 3);   // source-side swizzled k-chunk
    const int swr = (fr & 3) << 3;             // read-side swizzle
    constexpr int NT = K1P / 32;   // 10

    auto stage = [&](int buf, int kt) {
        const int k0 = kt * 32;
#pragma unroll
        for (int i = 0; i < 2; ++i) {
            int grp = i * 4 + wid;
            int grow = m0 + grp * 16 + arow;
            if (grow >= N_NODES) grow = N_NODES - 1;
            const unsigned short* ga = A + (size_t)grow * K1P + k0 + sk;
            __builtin_amdgcn_global_load_lds((const __attribute__((address_space(1))) void*)ga,
                                             (__attribute__((address_space(3))) void*)&tA[buf][grp * 512],
                                             16, 0, 0);
            int gn = n0 + grp * 16 + arow;
            const unsigned short* gb = Bt + (size_t)gn * K1P + k0 + sk;
            __builtin_amdgcn_global_load_lds((const __attribute__((address_space(1))) void*)gb,
                                             (__attribute__((address_space(3))) void*)&tB[buf][grp * 512],
                                             16, 0, 0);
        }
    };

    stage(0, 0);
    __syncthreads();

    int cur = 0;
    for (int kt = 0; kt < NT; ++kt) {
        if (kt + 1 < NT) stage(cur ^ 1, kt + 1);

        f16x8 af[4], bfr[4];
#pragma unroll
        for (int t = 0; t < 4; ++t) {
            af[t]  = *(const f16x8*)&tA[cur][(wm * 64 + t * 16 + fr) * 32 + (fq * 8 ^ swr)];
            bfr[t] = *(const f16x8*)&tB[cur][(wn * 64 + t * 16 + fr) * 32 + (fq * 8 ^ swr)];
        }
#pragma unroll
        for (int mt = 0; mt < 4; ++mt)
#pragma unroll
            for (int nt = 0; nt < 4; ++nt)
                acc[mt][nt] = __builtin_amdgcn_mfma_f32_16x16x32_f16(af[mt], bfr[nt], acc[mt][nt], 0, 0, 0);

        __syncthreads();
        cur ^= 1;
    }

    // epilogue
    float bv[4];
#pragma unroll
    for (int nt = 0; nt < 4; ++nt) {
        int col = n0 + wn * 64 + nt * 16 + fr;
        bv[nt] = (col < HDIM2) ? bias[col] : 0.f;
    }
    if (tid < 128) { csum[tid] = 0.f; cssq[tid] = 0.f; }
    __syncthreads();

    float colS[4] = {0.f, 0.f, 0.f, 0.f};
    float colQ[4] = {0.f, 0.f, 0.f, 0.f};
#pragma unroll
    for (int mt = 0; mt < 4; ++mt) {
#pragma unroll
        for (int r = 0; r < 4; ++r) {
            int row = m0 + wm * 64 + mt * 16 + fq * 4 + r;
            bool rok = row < N_NODES;
#pragma unroll
            for (int nt = 0; nt < 4; ++nt) {
                int col = n0 + wn * 64 + nt * 16 + fr;
                if (rok && col < HDIM2) {
                    float v = acc[mt][nt][r] + bv[nt];
                    Ch[(size_t)row * N1P + col] = f2h(v);
                    colS[nt] += v;
                    colQ[nt] += v * v;
                }
            }
        }
    }
#pragma unroll
    for (int nt = 0; nt < 4; ++nt) {
        int c = wn * 64 + nt * 16 + fr;
        atomicAdd(&csum[c], colS[nt]);
        atomicAdd(&cssq[c], colQ[nt]);
    }
    __syncthreads();
    if (tid < 128) {
        int col = n0 + tid;
        if (col < HDIM2) {
            atomicAdd(&gsum[col], csum[tid]);
            atomicAdd(&gssq[col], cssq[tid]);
        }
    }
}

// ---------- GEMM2: 128x128, 4 waves, BK=32; raw z1 staged (swizzled), bn1+relu in-reg ----------
__global__ __launch_bounds__(256, 3) void k_mfma2(const unsigned short* __restrict__ z1,
                                                  const unsigned short* __restrict__ Bt,
                                                  const float* __restrict__ bias,
                                                  const unsigned short* __restrict__ scaleAh,
                                                  const unsigned short* __restrict__ shiftAh,
                                                  unsigned short* __restrict__ Ch,
                                                  float* __restrict__ gsum,
                                                  float* __restrict__ gssq) {
    __shared__ unsigned short tA[2][128 * 32];
    __shared__ unsigned short tB[2][128 * 32];
    __shared__ float csum[128], cssq[128];

    const int tid = threadIdx.x;
    const int lane = tid & 63, wid = tid >> 6;
    const int wm = wid >> 1, wn = wid & 1;
    const int wgid = xcd_swz(blockIdx.x, NWG2);
    const int n0 = (wgid % 3) * 128, m0 = (wgid / 3) * 128;
    const int fr = lane & 15, fq = lane >> 4;

    f32x4 acc[4][4] = {};
    const int arow = lane >> 2;
    const int achk = (lane & 3) * 8;
    const int sk = achk ^ ((arow & 3) << 3);
    const int swr = (fr & 3) << 3;
    constexpr int NT = N1P / 32;   // 20

    auto stage = [&](int buf, int kt) {
        const int k0 = kt * 32;
#pragma unroll
        for (int i = 0; i < 2; ++i) {
            int grp = i * 4 + wid;
            int grow = m0 + grp * 16 + arow;
            if (grow >= N_NODES) grow = N_NODES - 1;
            const unsigned short* ga = z1 + (size_t)grow * N1P + k0 + sk;
            __builtin_amdgcn_global_load_lds((const __attribute__((address_space(1))) void*)ga,
                                             (__attribute__((address_space(3))) void*)&tA[buf][grp * 512],
                                             16, 0, 0);
            int gn = n0 + grp * 16 + arow;
            const unsigned short* gb = Bt + (size_t)gn * N1P + k0 + sk;
            __builtin_amdgcn_global_load_lds((const __attribute__((address_space(1))) void*)gb,
                                             (__attribute__((address_space(3))) void*)&tB[buf][grp * 512],
                                             16, 0, 0);
        }
    };

    stage(0, 0);
    __syncthreads();

    int cur = 0;
    for (int kt = 0; kt < NT; ++kt) {
        if (kt + 1 < NT) stage(cur ^ 1, kt + 1);

        const int kc = kt * 32 + fq * 8;
        f16x8 sa = *(const f16x8*)&scaleAh[kc];
        f16x8 sb = *(const f16x8*)&shiftAh[kc];
        f16x8 af[4], bfr[4];
#pragma unroll
        for (int t = 0; t < 4; ++t) {
            f16x8 z = *(const f16x8*)&tA[cur][(wm * 64 + t * 16 + fr) * 32 + (fq * 8 ^ swr)];
            f16x8 r;
#pragma unroll
            for (int j = 0; j < 8; ++j) {
                _Float16 v = z[j] * sa[j] + sb[j];
                r[j] = (v > (_Float16)0) ? v : (_Float16)0;
            }
            af[t] = r;
            bfr[t] = *(const f16x8*)&tB[cur][(wn * 64 + t * 16 + fr) * 32 + (fq * 8 ^ swr)];
        }
#pragma unroll
        for (int mt = 0; mt < 4; ++mt)
#pragma unroll
            for (int nt = 0; nt < 4; ++nt)
                acc[mt][nt] = __builtin_amdgcn_mfma_f32_16x16x32_f16(af[mt], bfr[nt], acc[mt][nt], 0, 0, 0);

        __syncthreads();
        cur ^= 1;
    }

    // epilogue (NC=300, stride K1P; pad cols never read -> not written)
    float bv[4];
#pragma unroll
    for (int nt = 0; nt < 4; ++nt) {
        int col = n0 + wn * 64 + nt * 16 + fr;
        bv[nt] = (col < HDIM) ? bias[col] : 0.f;
    }
    if (tid < 128) { csum[tid] = 0.f; cssq[tid] = 0.f; }
    __syncthreads();

    float colS[4] = {0.f, 0.f, 0.f, 0.f};
    float colQ[4] = {0.f, 0.f, 0.f, 0.f};
#pragma unroll
    for (int mt = 0; mt < 4; ++mt) {
#pragma unroll
        for (int r = 0; r < 4; ++r) {
            int row = m0 + wm * 64 + mt * 16 + fq * 4 + r;
            bool rok = row < N_NODES;
#pragma unroll
            for (int nt = 0; nt < 4; ++nt) {
                int col = n0 + wn * 64 + nt * 16 + fr;
                if (rok && col < HDIM) {
                    float v = acc[mt][nt][r] + bv[nt];
                    Ch[(size_t)row * K1P + col] = f2h(v);
                    colS[nt] += v;
                    colQ[nt] += v * v;
                }
            }
        }
    }
#pragma unroll
    for (int nt = 0; nt < 4; ++nt) {
        int c = wn * 64 + nt * 16 + fr;
        atomicAdd(&csum[c], colS[nt]);
        atomicAdd(&cssq[c], colQ[nt]);
    }
    __syncthreads();
    if (tid < 128) {
        int col = n0 + tid;
        if (col < HDIM) {
            atomicAdd(&gsum[col], csum[tid]);
            atomicAdd(&gssq[col], cssq[tid]);
        }
    }
}

// ---------- BN finalize (+ optional f16 scale/shift); zero other stats ----------
__global__ void k_fin(const float* __restrict__ gsum, const float* __restrict__ gssq,
                      const float* __restrict__ gamma, const float* __restrict__ beta,
                      int C, int CPAD, float* __restrict__ scale, float* __restrict__ shift,
                      unsigned short* scaleh, unsigned short* shifth,
                      float* zs, float* zq, int CZ) {
    int i = blockIdx.x * blockDim.x + threadIdx.x;
    if (i < CPAD) {
        float sc = 0.f, sh = 0.f;
        if (i < C) {
            float m = gsum[i] * (1.f / (float)N_NODES);
            float v = gssq[i] * (1.f / (float)N_NODES) - m * m;
            float rs = rsqrtf(v + 1e-5f);
            sc = rs * gamma[i];
            sh = beta[i] - m * sc;
        }
        scale[i] = sc;
        shift[i] = sh;
        if (scaleh) { scaleh[i] = f2h(sc); shifth[i] = f2h(sh); }
    }
    if (i < CZ) { zs[i] = 0.f; zq[i] = 0.f; }
}

// ---------- fused final BN + global add pool: z2 (f16) -> out_h (f32) + xpool ----------
__global__ __launch_bounds__(128) void k_poolnorm(const unsigned short* __restrict__ z2,
                                                  const float* __restrict__ scale,
                                                  const float* __restrict__ shift,
                                                  const int* __restrict__ batch,
                                                  float* __restrict__ out_h,
                                                  float* __restrict__ xpool) {
    int g = blockIdx.x;
    int t = threadIdx.x;
    int start = lower_bound_i(batch, N_NODES, g);
    int end   = lower_bound_i(batch, N_NODES, g + 1);
    int cols[3] = { t, t + 128, t + 256 };
    float scv[3] = {0.f, 0.f, 0.f}, shv[3] = {0.f, 0.f, 0.f};
    float acc[3] = {0.f, 0.f, 0.f};
#pragma unroll
    for (int q = 0; q < 3; ++q) {
        int c = cols[q];
        if (c < HDIM) { scv[q] = scale[c]; shv[q] = shift[c]; }
    }
    for (int n = start; n < end; ++n) {
        const unsigned short* zr = z2 + (size_t)n * K1P;
        float* hr = out_h + (size_t)n * HDIM;
#pragma unroll
        for (int q = 0; q < 3; ++q) {
            int c = cols[q];
            if (c < HDIM) {
                float v = h2f(zr[c]) * scv[q] + shv[q];
                hr[c] = v;
                acc[q] += v;
            }
        }
    }
#pragma unroll
    for (int q = 0; q < 3; ++q)
        if (cols[q] < HDIM) xpool[(size_t)g * HDIM + cols[q]] = acc[q];
}

extern "C" void kernel_launch(void* const* d_in, const int* in_sizes, int n_in,
                              void* d_out, int out_size, void* d_ws, size_t ws_size,
                              hipStream_t stream) {
    const int*   batch    = (const int*)d_in[0];
    const int*   x        = (const int*)d_in[1];
    const int*   eidx     = (const int*)d_in[2];     // [2][E]
    const int*   eattr    = (const int*)d_in[3];     // [E][3]
    const float* atom_emb = (const float*)d_in[4];
    const float* bond_emb = (const float*)d_in[5];
    const float* W1 = (const float*)d_in[6];
    const float* b1 = (const float*)d_in[7];
    const float* g1 = (const float*)d_in[8];
    const float* be1 = (const float*)d_in[9];
    const float* W2 = (const float*)d_in[10];
    const float* b2 = (const float*)d_in[11];
    const float* g2 = (const float*)d_in[12];
    const float* be2 = (const float*)d_in[13];

    const int* src = eidx;
    const int* dst = eidx + N_EDGES;

    float* out_h    = (float*)d_out;                           // [N][300]
    float* out_pool = (float*)d_out + (size_t)N_NODES * HDIM;  // [G][300]

    char* ws = (char*)d_ws;
    size_t off = 0;
    auto alloc = [&](size_t bytes) -> void* {
        void* p = ws + off;
        off += (bytes + 255) & ~(size_t)255;
        return p;
    };
    unsigned short* hf    = (unsigned short*)alloc((size_t)N_NODES * K1P * 2);      // f16 [N][320]
    unsigned short* zin   = (unsigned short*)alloc((size_t)N_NODES * K1P * 2);      // f16 [N][320]
    unsigned short* z1    = (unsigned short*)alloc((size_t)N_NODES * N1P * 2);      // f16 [N][640]
    unsigned short* z2    = (unsigned short*)alloc((size_t)N_NODES * K1P * 2);      // f16 [N][320]
    unsigned short* W1t   = (unsigned short*)alloc((size_t)NLAYER * N1P * K1P * 2); // [5][640][320]
    unsigned short* W2t   = (unsigned short*)alloc((size_t)NLAYER * N2P * N1P * 2); // [5][384][640]
    unsigned short* ecomb = (unsigned short*)alloc((size_t)NCOMBO * HDIM * 2);      // f16 [4096][300]
    int* rowptr  = (int*)alloc((N_NODES + 1) * sizeof(int));
    int* deg     = (int*)alloc(N_NODES * sizeof(int));
    int* fill    = (int*)alloc(N_NODES * sizeof(int));
    int* part    = (int*)alloc(N_NODES * sizeof(int));
    int* psum    = (int*)alloc(64 * sizeof(int));
    int2* csr_rec = (int2*)alloc((size_t)N_EDGES * sizeof(int2));
    float* s1     = (float*)alloc(N1P * sizeof(float));
    float* q1     = (float*)alloc(N1P * sizeof(float));
    float* scale1 = (float*)alloc(N1P * sizeof(float));
    float* shift1 = (float*)alloc(N1P * sizeof(float));
    unsigned short* scale1h = (unsigned short*)alloc(N1P * sizeof(short));
    unsigned short* shift1h = (unsigned short*)alloc(N1P * sizeof(short));
    float* s2     = (float*)alloc(K1P * sizeof(float));
    float* q2     = (float*)alloc(K1P * sizeof(float));
    float* scale2 = (float*)alloc(K1P * sizeof(float));
    float* shift2 = (float*)alloc(K1P * sizeof(float));

    // setup
    k_init<<<(N_NODES + 255) / 256, 256, 0, stream>>>(deg, fill, s1, q1, s2, q2);
    k_atom<<<(N_NODES * K1P + 255) / 256, 256, 0, stream>>>(x, atom_emb, hf);
    k_ecomb<<<(NCOMBO * HDIM + 255) / 256, 256, 0, stream>>>(bond_emb, ecomb);
    k_deg<<<(N_EDGES + 255) / 256, 256, 0, stream>>>(dst, deg);
    k_scan1<<<NSCAN, SCAN_BLK, 0, stream>>>(deg, part, psum);
    k_scan2<<<1, 64, 0, stream>>>(psum);
    k_scan3<<<(N_NODES + 255) / 256, 256, 0, stream>>>(part, psum, rowptr);
    k_fill<<<(N_EDGES + 255) / 256, 256, 0, stream>>>(src, dst, eattr, rowptr,
                                                      fill, csr_rec);
    {
        int tot1 = NLAYER * N1P * K1P;
        k_wconv<<<(tot1 + 255) / 256, 256, 0, stream>>>(W1, W1t, HDIM, HDIM2, K1P, N1P);
        int tot2 = NLAYER * N2P * N1P;
        k_wconv<<<(tot2 + 255) / 256, 256, 0, stream>>>(W2, W2t, HDIM2, HDIM, N1P, N2P);
    }

    int msg_grid = (N_NODES + 3) / 4;
    for (int l = 0; l < NLAYER; ++l) {
        if (l == 0) {
            k_msg<false><<<msg_grid, 256, 0, stream>>>(hf, nullptr, nullptr,
                                                       rowptr, csr_rec, ecomb, zin);
        } else {
            k_msg<true><<<msg_grid, 256, 0, stream>>>(z2, scale2, shift2,
                                                      rowptr, csr_rec, ecomb, zin);
        }

        k_mfma1<<<NWG1, 256, 0, stream>>>(
            zin, W1t + (size_t)l * N1P * K1P, b1 + (size_t)l * HDIM2, z1, s1, q1);

        k_fin<<<3, 256, 0, stream>>>(s1, q1, g1 + (size_t)l * HDIM2, be1 + (size_t)l * HDIM2,
                                     HDIM2, N1P, scale1, shift1, scale1h, shift1h,
                                     s2, q2, K1P);

        k_mfma2<<<NWG2, 256, 0, stream>>>(
            z1, W2t + (size_t)l * N2P * N1P, b2 + (size_t)l * HDIM,
            scale1h, shift1h, z2, s2, q2);

        k_fin<<<3, 256, 0, stream>>>(s2, q2, g2 + (size_t)l * HDIM, be2 + (size_t)l * HDIM,
                                     HDIM, K1P, scale2, shift2, nullptr, nullptr,
                                     s1, q1, N1P);
    }

    k_poolnorm<<<N_GRAPHS, 128, 0, stream>>>(z2, scale2, shift2, batch, out_h, out_pool);
}

// Round 18
// 1015.787 us; speedup vs baseline: 1.6813x; 1.0232x over previous
//
#include <hip/hip_runtime.h>

#define N_NODES 50000
#define N_EDGES 200000
#define N_GRAPHS 2048
#define HDIM 300
#define HDIM2 600
#define NLAYER 5
// padded dims for MFMA
#define K1P 320     // GEMM1 K (300 -> 320), h/zin/z2 storage stride
#define N1P 640     // GEMM1 N (600 -> 640), also GEMM2 K
#define N2P 384     // W2t row allocation (rows 300..383 zero)

#define MT1 ((N_NODES + 127) / 128)   // 391 m-tiles
#define NWG1 (5 * MT1)                // 1955
#define NWG2 (3 * MT1)                // 1173

#define NCOMBO 4096                   // 16^3 bond-attr combos

#define SCAN_BLK 1024
#define NSCAN ((N_NODES + SCAN_BLK - 1) / SCAN_BLK)   // 49

#define RN (1.f / (float)N_NODES)

typedef __attribute__((ext_vector_type(8))) _Float16 f16x8;
typedef __attribute__((ext_vector_type(8))) unsigned short ushort8;
typedef __attribute__((ext_vector_type(4))) float f32x4;

__device__ __forceinline__ unsigned short f2h(float f) {
    _Float16 h = (_Float16)f;                      // RNE
    return __builtin_bit_cast(unsigned short, h);
}
__device__ __forceinline__ float h2f(unsigned short u) {
    _Float16 h = __builtin_bit_cast(_Float16, u);
    return (float)h;
}

__device__ __forceinline__ int lower_bound_i(const int* a, int n, int key) {
    int lo = 0, hi = n;
    while (lo < hi) { int mid = (lo + hi) >> 1; if (a[mid] < key) lo = mid + 1; else hi = mid; }
    return lo;
}

// bijective XCD chunking (m204)
__device__ __forceinline__ int xcd_swz(int orig, int nwg) {
    int q = nwg >> 3, r = nwg & 7;
    int xcd = orig & 7;
    int base = (xcd < r) ? xcd * (q + 1) : r * (q + 1) + (xcd - r) * q;
    return base + (orig >> 3);
}

// ---------- init: zero counters and ALL per-layer stats buffers ----------
__global__ void k_init(int* deg, int* fill, float* s1a, float* q1a, float* s2a, float* q2a) {
    int i = blockIdx.x * blockDim.x + threadIdx.x;
    if (i < N_NODES) { deg[i] = 0; fill[i] = 0; }
    if (i < NLAYER * N1P) { s1a[i] = 0.f; q1a[i] = 0.f; }
    if (i < NLAYER * K1P) { s2a[i] = 0.f; q2a[i] = 0.f; }
}

// ---------- atom encoder ----------
__global__ void k_atom(const int* __restrict__ x, const float* __restrict__ atom_emb,
                       unsigned short* __restrict__ hf) {
    int idx = blockIdx.x * blockDim.x + threadIdx.x;
    if (idx >= N_NODES * K1P) return;
    int n = idx / K1P;
    int c = idx - n * K1P;
    if (c >= HDIM) { hf[idx] = 0; return; }
    const int* xr = x + n * 9;
    float acc = 0.f;
#pragma unroll
    for (int f = 0; f < 9; ++f) {
        int row = xr[f] + f * 128;
        acc += atom_emb[(size_t)row * HDIM + c];
    }
    hf[idx] = f2h(acc);
}

// ---------- bond combo table ----------
__global__ void k_ecomb(const float* __restrict__ bond_emb, unsigned short* __restrict__ ecomb) {
    int t = blockIdx.x * blockDim.x + threadIdx.x;
    if (t >= NCOMBO * HDIM) return;
    int idx = t / HDIM, c = t - idx * HDIM;
    int a0 = idx & 15, a1 = (idx >> 4) & 15, a2 = idx >> 8;
    float v = bond_emb[(size_t)a0 * HDIM + c]
            + bond_emb[(size_t)(16 + a1) * HDIM + c]
            + bond_emb[(size_t)(32 + a2) * HDIM + c];
    ecomb[t] = f2h(v);
}

// ---------- CSR build over dst ----------
__global__ void k_deg(const int* __restrict__ dst, int* deg) {
    int j = blockIdx.x * blockDim.x + threadIdx.x;
    if (j < N_EDGES) atomicAdd(&deg[dst[j]], 1);
}

__global__ void k_scan1(const int* __restrict__ deg, int* __restrict__ part,
                        int* __restrict__ psum) {
    __shared__ int buf[SCAN_BLK];
    int b = blockIdx.x, tid = threadIdx.x;
    int i = b * SCAN_BLK + tid;
    int v = (i < N_NODES) ? deg[i] : 0;
    buf[tid] = v;
    __syncthreads();
    for (int off = 1; off < SCAN_BLK; off <<= 1) {
        int t = (tid >= off) ? buf[tid - off] : 0;
        __syncthreads();
        buf[tid] += t;
        __syncthreads();
    }
    if (i < N_NODES) part[i] = buf[tid];
    if (tid == SCAN_BLK - 1) psum[b] = buf[tid];
}

__global__ void k_scan2(int* __restrict__ psum) {
    __shared__ int buf[64];
    int tid = threadIdx.x;
    int v = (tid < NSCAN) ? psum[tid] : 0;
    buf[tid] = v;
    __syncthreads();
    for (int off = 1; off < 64; off <<= 1) {
        int t = (tid >= off) ? buf[tid - off] : 0;
        __syncthreads();
        buf[tid] += t;
        __syncthreads();
    }
    if (tid < NSCAN) psum[tid] = buf[tid] - v;
}

__global__ void k_scan3(const int* __restrict__ part, const int* __restrict__ psum,
                        int* __restrict__ rowptr) {
    int i = blockIdx.x * blockDim.x + threadIdx.x;
    if (i == 0) rowptr[0] = 0;
    if (i < N_NODES) rowptr[i + 1] = part[i] + psum[i / SCAN_BLK];
}

// fill packed CSR records: int2 {src, combo idx}
__global__ void k_fill(const int* __restrict__ src, const int* __restrict__ dst,
                       const int* __restrict__ eattr, const int* __restrict__ rowptr,
                       int* fill, int2* __restrict__ csr_rec) {
    int j = blockIdx.x * blockDim.x + threadIdx.x;
    if (j < N_EDGES) {
        int d = dst[j];
        int p = atomicAdd(&fill[d], 1);
        int pos = rowptr[d] + p;
        int combo = eattr[j * 3 + 0] | (eattr[j * 3 + 1] << 4) | (eattr[j * 3 + 2] << 8);
        csr_rec[pos] = make_int2(src[j], combo);
    }
}

// ---------- weight transpose + f16 convert ----------
__global__ void k_wconv(const float* __restrict__ W, unsigned short* __restrict__ Bt,
                        int K, int NC, int KPAD, int NPAD) {
    int idx = blockIdx.x * blockDim.x + threadIdx.x;
    int tot = NLAYER * NPAD * KPAD;
    if (idx >= tot) return;
    int l = idx / (NPAD * KPAD);
    int rem = idx - l * NPAD * KPAD;
    int n = rem / KPAD;
    int k = rem - n * KPAD;
    float v = (k < K && n < NC) ? W[((size_t)l * K + k) * NC + n] : 0.f;
    Bt[idx] = f2h(v);
}

// ---------- message passing: one node per wave, 4 waves/block ----------
// BN: inline bn2 finalize from raw stats of the PREVIOUS layer.
template <bool BN>
__global__ __launch_bounds__(256) void k_msg(const unsigned short* __restrict__ hsrc,
                                             const float* __restrict__ s2p,
                                             const float* __restrict__ q2p,
                                             const float* __restrict__ g2p,
                                             const float* __restrict__ be2p,
                                             const int* __restrict__ rowptr,
                                             const int2* __restrict__ csr_rec,
                                             const unsigned short* __restrict__ ecomb,
                                             unsigned short* __restrict__ zin) {
    int wid = threadIdx.x >> 6, lane = threadIdx.x & 63;
    int n = blockIdx.x * 4 + wid;
    if (n >= N_NODES) return;

    float scv[5], shv[5], acc[5];
#pragma unroll
    for (int q = 0; q < 5; ++q) {
        int c = lane + 64 * q;
        scv[q] = 0.f; shv[q] = 0.f; acc[q] = 0.f;
        if (c < HDIM) {
            if (BN) {
                float m = s2p[c] * RN;
                float vv = q2p[c] * RN - m * m;
                float rs = rsqrtf(vv + 1e-5f);
                scv[q] = rs * g2p[c];
                shv[q] = be2p[c] - m * scv[q];
            }
            float v = h2f(hsrc[(size_t)n * K1P + c]);
            if (BN) v = fmaxf(v * scv[q] + shv[q], 0.f);
            acc[q] = v;
        }
    }

    int beg = rowptr[n], end = rowptr[n + 1];
    int p = beg;
    for (; p + 2 <= end; p += 2) {
        int2 r0 = csr_rec[p];
        int2 r1 = csr_rec[p + 1];
        const unsigned short* h0 = hsrc + (size_t)r0.x * K1P;
        const unsigned short* h1 = hsrc + (size_t)r1.x * K1P;
        const unsigned short* e0 = ecomb + (size_t)r0.y * HDIM;
        const unsigned short* e1 = ecomb + (size_t)r1.y * HDIM;
#pragma unroll
        for (int q = 0; q < 5; ++q) {
            int c = lane + 64 * q;
            if (c < HDIM) {
                float v0 = h2f(h0[c]);
                float v1 = h2f(h1[c]);
                if (BN) {
                    v0 = fmaxf(v0 * scv[q] + shv[q], 0.f);
                    v1 = fmaxf(v1 * scv[q] + shv[q], 0.f);
                }
                float m0 = v0 + h2f(e0[c]);
                float m1 = v1 + h2f(e1[c]);
                acc[q] += fmaxf(m0, 0.f) + fmaxf(m1, 0.f);
            }
        }
    }
    if (p < end) {
        int2 r0 = csr_rec[p];
        const unsigned short* h0 = hsrc + (size_t)r0.x * K1P;
        const unsigned short* e0 = ecomb + (size_t)r0.y * HDIM;
#pragma unroll
        for (int q = 0; q < 5; ++q) {
            int c = lane + 64 * q;
            if (c < HDIM) {
                float v0 = h2f(h0[c]);
                if (BN) v0 = fmaxf(v0 * scv[q] + shv[q], 0.f);
                float m0 = v0 + h2f(e0[c]);
                acc[q] += fmaxf(m0, 0.f);
            }
        }
    }
    unsigned short* zr = zin + (size_t)n * K1P;
#pragma unroll
    for (int q = 0; q < 5; ++q) {
        int c = lane + 64 * q;
        if (c < HDIM) zr[c] = f2h(acc[q]);
    }
}

// ---------- GEMM1: 128x128 tile, 4 waves, BK=32, gload_lds, 2-phase (best-known) ----------
__global__ __launch_bounds__(256, 4) void k_mfma1(const unsigned short* __restrict__ A,
                                                  const unsigned short* __restrict__ Bt,
                                                  const float* __restrict__ bias,
                                                  unsigned short* __restrict__ Ch,
                                                  float* __restrict__ gsum,
                                                  float* __restrict__ gssq) {
    __shared__ unsigned short tA[2][128 * 32];
    __shared__ unsigned short tB[2][128 * 32];
    __shared__ float csum[128], cssq[128];

    const int tid = threadIdx.x;
    const int lane = tid & 63, wid = tid >> 6;
    const int wm = wid >> 1, wn = wid & 1;
    const int wgid = xcd_swz(blockIdx.x, NWG1);
    const int n0 = (wgid % 5) * 128, m0 = (wgid / 5) * 128;
    const int fr = lane & 15, fq = lane >> 4;

    f32x4 acc[4][4] = {};
    const int arow = lane >> 2;
    const int achk = (lane & 3) * 8;
    const int sk = achk ^ ((arow & 3) << 3);   // source-side swizzled k-chunk
    const int swr = (fr & 3) << 3;             // read-side swizzle
    constexpr int NT = K1P / 32;   // 10

    auto stage = [&](int buf, int kt) {
        const int k0 = kt * 32;
#pragma unroll
        for (int i = 0; i < 2; ++i) {
            int grp = i * 4 + wid;
            int grow = m0 + grp * 16 + arow;
            if (grow >= N_NODES) grow = N_NODES - 1;
            const unsigned short* ga = A + (size_t)grow * K1P + k0 + sk;
            __builtin_amdgcn_global_load_lds((const __attribute__((address_space(1))) void*)ga,
                                             (__attribute__((address_space(3))) void*)&tA[buf][grp * 512],
                                             16, 0, 0);
            int gn = n0 + grp * 16 + arow;
            const unsigned short* gb = Bt + (size_t)gn * K1P + k0 + sk;
            __builtin_amdgcn_global_load_lds((const __attribute__((address_space(1))) void*)gb,
                                             (__attribute__((address_space(3))) void*)&tB[buf][grp * 512],
                                             16, 0, 0);
        }
    };

    stage(0, 0);
    __syncthreads();

    int cur = 0;
    for (int kt = 0; kt < NT; ++kt) {
        if (kt + 1 < NT) stage(cur ^ 1, kt + 1);

        f16x8 af[4], bfr[4];
#pragma unroll
        for (int t = 0; t < 4; ++t) {
            af[t]  = *(const f16x8*)&tA[cur][(wm * 64 + t * 16 + fr) * 32 + (fq * 8 ^ swr)];
            bfr[t] = *(const f16x8*)&tB[cur][(wn * 64 + t * 16 + fr) * 32 + (fq * 8 ^ swr)];
        }
#pragma unroll
        for (int mt = 0; mt < 4; ++mt)
#pragma unroll
            for (int nt = 0; nt < 4; ++nt)
                acc[mt][nt] = __builtin_amdgcn_mfma_f32_16x16x32_f16(af[mt], bfr[nt], acc[mt][nt], 0, 0, 0);

        __syncthreads();
        cur ^= 1;
    }

    // epilogue
    float bv[4];
#pragma unroll
    for (int nt = 0; nt < 4; ++nt) {
        int col = n0 + wn * 64 + nt * 16 + fr;
        bv[nt] = (col < HDIM2) ? bias[col] : 0.f;
    }
    if (tid < 128) { csum[tid] = 0.f; cssq[tid] = 0.f; }
    __syncthreads();

    float colS[4] = {0.f, 0.f, 0.f, 0.f};
    float colQ[4] = {0.f, 0.f, 0.f, 0.f};
#pragma unroll
    for (int mt = 0; mt < 4; ++mt) {
#pragma unroll
        for (int r = 0; r < 4; ++r) {
            int row = m0 + wm * 64 + mt * 16 + fq * 4 + r;
            bool rok = row < N_NODES;
#pragma unroll
            for (int nt = 0; nt < 4; ++nt) {
                int col = n0 + wn * 64 + nt * 16 + fr;
                if (rok && col < HDIM2) {
                    float v = acc[mt][nt][r] + bv[nt];
                    Ch[(size_t)row * N1P + col] = f2h(v);
                    colS[nt] += v;
                    colQ[nt] += v * v;
                }
            }
        }
    }
#pragma unroll
    for (int nt = 0; nt < 4; ++nt) {
        int c = wn * 64 + nt * 16 + fr;
        atomicAdd(&csum[c], colS[nt]);
        atomicAdd(&cssq[c], colQ[nt]);
    }
    __syncthreads();
    if (tid < 128) {
        int col = n0 + tid;
        if (col < HDIM2) {
            atomicAdd(&gsum[col], csum[tid]);
            atomicAdd(&gssq[col], cssq[tid]);
        }
    }
}

// ---------- GEMM2: 128x128, 4 waves, BK=32; bn1 finalize inline (LDS prologue) ----------
__global__ __launch_bounds__(256, 3) void k_mfma2(const unsigned short* __restrict__ z1,
                                                  const unsigned short* __restrict__ Bt,
                                                  const float* __restrict__ bias,
                                                  const float* __restrict__ gs1,
                                                  const float* __restrict__ gq1,
                                                  const float* __restrict__ gamma1,
                                                  const float* __restrict__ beta1,
                                                  unsigned short* __restrict__ Ch,
                                                  float* __restrict__ gsum,
                                                  float* __restrict__ gssq) {
    __shared__ unsigned short tA[2][128 * 32];
    __shared__ unsigned short tB[2][128 * 32];
    __shared__ float csum[128], cssq[128];
    __shared__ __attribute__((aligned(16))) unsigned short sLDS[N1P];
    __shared__ __attribute__((aligned(16))) unsigned short hLDS[N1P];

    const int tid = threadIdx.x;
    const int lane = tid & 63, wid = tid >> 6;
    const int wm = wid >> 1, wn = wid & 1;
    const int wgid = xcd_swz(blockIdx.x, NWG2);
    const int n0 = (wgid % 3) * 128, m0 = (wgid / 3) * 128;
    const int fr = lane & 15, fq = lane >> 4;

    f32x4 acc[4][4] = {};
    const int arow = lane >> 2;
    const int achk = (lane & 3) * 8;
    const int sk = achk ^ ((arow & 3) << 3);
    const int swr = (fr & 3) << 3;
    constexpr int NT = N1P / 32;   // 20

    auto stage = [&](int buf, int kt) {
        const int k0 = kt * 32;
#pragma unroll
        for (int i = 0; i < 2; ++i) {
            int grp = i * 4 + wid;
            int grow = m0 + grp * 16 + arow;
            if (grow >= N_NODES) grow = N_NODES - 1;
            const unsigned short* ga = z1 + (size_t)grow * N1P + k0 + sk;
            __builtin_amdgcn_global_load_lds((const __attribute__((address_space(1))) void*)ga,
                                             (__attribute__((address_space(3))) void*)&tA[buf][grp * 512],
                                             16, 0, 0);
            int gn = n0 + grp * 16 + arow;
            const unsigned short* gb = Bt + (size_t)gn * N1P + k0 + sk;
            __builtin_amdgcn_global_load_lds((const __attribute__((address_space(1))) void*)gb,
                                             (__attribute__((address_space(3))) void*)&tB[buf][grp * 512],
                                             16, 0, 0);
        }
    };

    stage(0, 0);
    // inline bn1 finalize: scale/shift (f16) into LDS, cols 0..639 (pad -> 0)
    for (int c = tid; c < N1P; c += 256) {
        float sc = 0.f, sh = 0.f;
        if (c < HDIM2) {
            float m = gs1[c] * RN;
            float vv = gq1[c] * RN - m * m;
            float rs = rsqrtf(vv + 1e-5f);
            sc = rs * gamma1[c];
            sh = beta1[c] - m * sc;
        }
        sLDS[c] = f2h(sc);
        hLDS[c] = f2h(sh);
    }
    __syncthreads();

    int cur = 0;
    for (int kt = 0; kt < NT; ++kt) {
        if (kt + 1 < NT) stage(cur ^ 1, kt + 1);

        const int kc = kt * 32 + fq * 8;
        f16x8 sa = *(const f16x8*)&sLDS[kc];
        f16x8 sb = *(const f16x8*)&hLDS[kc];
        f16x8 af[4], bfr[4];
#pragma unroll
        for (int t = 0; t < 4; ++t) {
            f16x8 z = *(const f16x8*)&tA[cur][(wm * 64 + t * 16 + fr) * 32 + (fq * 8 ^ swr)];
            f16x8 r;
#pragma unroll
            for (int j = 0; j < 8; ++j) {
                _Float16 v = z[j] * sa[j] + sb[j];
                r[j] = (v > (_Float16)0) ? v : (_Float16)0;
            }
            af[t] = r;
            bfr[t] = *(const f16x8*)&tB[cur][(wn * 64 + t * 16 + fr) * 32 + (fq * 8 ^ swr)];
        }
#pragma unroll
        for (int mt = 0; mt < 4; ++mt)
#pragma unroll
            for (int nt = 0; nt < 4; ++nt)
                acc[mt][nt] = __builtin_amdgcn_mfma_f32_16x16x32_f16(af[mt], bfr[nt], acc[mt][nt], 0, 0, 0);

        __syncthreads();
        cur ^= 1;
    }

    // epilogue (NC=300, stride K1P; pad cols never read -> not written)
    float bv[4];
#pragma unroll
    for (int nt = 0; nt < 4; ++nt) {
        int col = n0 + wn * 64 + nt * 16 + fr;
        bv[nt] = (col < HDIM) ? bias[col] : 0.f;
    }
    if (tid < 128) { csum[tid] = 0.f; cssq[tid] = 0.f; }
    __syncthreads();

    float colS[4] = {0.f, 0.f, 0.f, 0.f};
    float colQ[4] = {0.f, 0.f, 0.f, 0.f};
#pragma unroll
    for (int mt = 0; mt < 4; ++mt) {
#pragma unroll
        for (int r = 0; r < 4; ++r) {
            int row = m0 + wm * 64 + mt * 16 + fq * 4 + r;
            bool rok = row < N_NODES;
#pragma unroll
            for (int nt = 0; nt < 4; ++nt) {
                int col = n0 + wn * 64 + nt * 16 + fr;
                if (rok && col < HDIM) {
                    float v = acc[mt][nt][r] + bv[nt];
                    Ch[(size_t)row * K1P + col] = f2h(v);
                    colS[nt] += v;
                    colQ[nt] += v * v;
                }
            }
        }
    }
#pragma unroll
    for (int nt = 0; nt < 4; ++nt) {
        int c = wn * 64 + nt * 16 + fr;
        atomicAdd(&csum[c], colS[nt]);
        atomicAdd(&cssq[c], colQ[nt]);
    }
    __syncthreads();
    if (tid < 128) {
        int col = n0 + tid;
        if (col < HDIM) {
            atomicAdd(&gsum[col], csum[tid]);
            atomicAdd(&gssq[col], cssq[tid]);
        }
    }
}

// ---------- fused final BN (inline finalize) + global add pool ----------
__global__ __launch_bounds__(128) void k_poolnorm(const unsigned short* __restrict__ z2,
                                                  const float* __restrict__ s2p,
                                                  const float* __restrict__ q2p,
                                                  const float* __restrict__ g2p,
                                                  const float* __restrict__ be2p,
                                                  const int* __restrict__ batch,
                                                  float* __restrict__ out_h,
                                                  float* __restrict__ xpool) {
    int g = blockIdx.x;
    int t = threadIdx.x;
    int start = lower_bound_i(batch, N_NODES, g);
    int end   = lower_bound_i(batch, N_NODES, g + 1);
    int cols[3] = { t, t + 128, t + 256 };
    float scv[3] = {0.f, 0.f, 0.f}, shv[3] = {0.f, 0.f, 0.f};
    float acc[3] = {0.f, 0.f, 0.f};
#pragma unroll
    for (int q = 0; q < 3; ++q) {
        int c = cols[q];
        if (c < HDIM) {
            float m = s2p[c] * RN;
            float vv = q2p[c] * RN - m * m;
            float rs = rsqrtf(vv + 1e-5f);
            scv[q] = rs * g2p[c];
            shv[q] = be2p[c] - m * scv[q];
        }
    }
    for (int n = start; n < end; ++n) {
        const unsigned short* zr = z2 + (size_t)n * K1P;
        float* hr = out_h + (size_t)n * HDIM;
#pragma unroll
        for (int q = 0; q < 3; ++q) {
            int c = cols[q];
            if (c < HDIM) {
                float v = h2f(zr[c]) * scv[q] + shv[q];
                hr[c] = v;
                acc[q] += v;
            }
        }
    }
#pragma unroll
    for (int q = 0; q < 3; ++q)
        if (cols[q] < HDIM) xpool[(size_t)g * HDIM + cols[q]] = acc[q];
}

extern "C" void kernel_launch(void* const* d_in, const int* in_sizes, int n_in,
                              void* d_out, int out_size, void* d_ws, size_t ws_size,
                              hipStream_t stream) {
    const int*   batch    = (const int*)d_in[0];
    const int*   x        = (const int*)d_in[1];
    const int*   eidx     = (const int*)d_in[2];     // [2][E]
    const int*   eattr    = (const int*)d_in[3];     // [E][3]
    const float* atom_emb = (const float*)d_in[4];
    const float* bond_emb = (const float*)d_in[5];
    const float* W1 = (const float*)d_in[6];
    const float* b1 = (const float*)d_in[7];
    const float* g1 = (const float*)d_in[8];
    const float* be1 = (const float*)d_in[9];
    const float* W2 = (const float*)d_in[10];
    const float* b2 = (const float*)d_in[11];
    const float* g2 = (const float*)d_in[12];
    const float* be2 = (const float*)d_in[13];

    const int* src = eidx;
    const int* dst = eidx + N_EDGES;

    float* out_h    = (float*)d_out;                           // [N][300]
    float* out_pool = (float*)d_out + (size_t)N_NODES * HDIM;  // [G][300]

    char* ws = (char*)d_ws;
    size_t off = 0;
    auto alloc = [&](size_t bytes) -> void* {
        void* p = ws + off;
        off += (bytes + 255) & ~(size_t)255;
        return p;
    };
    unsigned short* hf    = (unsigned short*)alloc((size_t)N_NODES * K1P * 2);      // f16 [N][320]
    unsigned short* zin   = (unsigned short*)alloc((size_t)N_NODES * K1P * 2);      // f16 [N][320]
    unsigned short* z1    = (unsigned short*)alloc((size_t)N_NODES * N1P * 2);      // f16 [N][640]
    unsigned short* z2    = (unsigned short*)alloc((size_t)N_NODES * K1P * 2);      // f16 [N][320]
    unsigned short* W1t   = (unsigned short*)alloc((size_t)NLAYER * N1P * K1P * 2); // [5][640][320]
    unsigned short* W2t   = (unsigned short*)alloc((size_t)NLAYER * N2P * N1P * 2); // [5][384][640]
    unsigned short* ecomb = (unsigned short*)alloc((size_t)NCOMBO * HDIM * 2);      // f16 [4096][300]
    int* rowptr  = (int*)alloc((N_NODES + 1) * sizeof(int));
    int* deg     = (int*)alloc(N_NODES * sizeof(int));
    int* fill    = (int*)alloc(N_NODES * sizeof(int));
    int* part    = (int*)alloc(N_NODES * sizeof(int));
    int* psum    = (int*)alloc(64 * sizeof(int));
    int2* csr_rec = (int2*)alloc((size_t)N_EDGES * sizeof(int2));
    float* s1a = (float*)alloc((size_t)NLAYER * N1P * sizeof(float));
    float* q1a = (float*)alloc((size_t)NLAYER * N1P * sizeof(float));
    float* s2a = (float*)alloc((size_t)NLAYER * K1P * sizeof(float));
    float* q2a = (float*)alloc((size_t)NLAYER * K1P * sizeof(float));

    // setup
    k_init<<<(N_NODES + 255) / 256, 256, 0, stream>>>(deg, fill, s1a, q1a, s2a, q2a);
    k_atom<<<(N_NODES * K1P + 255) / 256, 256, 0, stream>>>(x, atom_emb, hf);
    k_ecomb<<<(NCOMBO * HDIM + 255) / 256, 256, 0, stream>>>(bond_emb, ecomb);
    k_deg<<<(N_EDGES + 255) / 256, 256, 0, stream>>>(dst, deg);
    k_scan1<<<NSCAN, SCAN_BLK, 0, stream>>>(deg, part, psum);
    k_scan2<<<1, 64, 0, stream>>>(psum);
    k_scan3<<<(N_NODES + 255) / 256, 256, 0, stream>>>(part, psum, rowptr);
    k_fill<<<(N_EDGES + 255) / 256, 256, 0, stream>>>(src, dst, eattr, rowptr,
                                                      fill, csr_rec);
    {
        int tot1 = NLAYER * N1P * K1P;
        k_wconv<<<(tot1 + 255) / 256, 256, 0, stream>>>(W1, W1t, HDIM, HDIM2, K1P, N1P);
        int tot2 = NLAYER * N2P * N1P;
        k_wconv<<<(tot2 + 255) / 256, 256, 0, stream>>>(W2, W2t, HDIM2, HDIM, N1P, N2P);
    }

    int msg_grid = (N_NODES + 3) / 4;
    for (int l = 0; l < NLAYER; ++l) {
        if (l == 0) {
            k_msg<false><<<msg_grid, 256, 0, stream>>>(hf, nullptr, nullptr, nullptr, nullptr,
                                                       rowptr, csr_rec, ecomb, zin);
        } else {
            k_msg<true><<<msg_grid, 256, 0, stream>>>(z2,
                                                      s2a + (size_t)(l - 1) * K1P,
                                                      q2a + (size_t)(l - 1) * K1P,
                                                      g2 + (size_t)(l - 1) * HDIM,
                                                      be2 + (size_t)(l - 1) * HDIM,
                                                      rowptr, csr_rec, ecomb, zin);
        }

        k_mfma1<<<NWG1, 256, 0, stream>>>(
            zin, W1t + (size_t)l * N1P * K1P, b1 + (size_t)l * HDIM2, z1,
            s1a + (size_t)l * N1P, q1a + (size_t)l * N1P);

        k_mfma2<<<NWG2, 256, 0, stream>>>(
            z1, W2t + (size_t)l * N2P * N1P, b2 + (size_t)l * HDIM,
            s1a + (size_t)l * N1P, q1a + (size_t)l * N1P,
            g1 + (size_t)l * HDIM2, be1 + (size_t)l * HDIM2,
            z2, s2a + (size_t)l * K1P, q2a + (size_t)l * K1P);
    }

    k_poolnorm<<<N_GRAPHS, 128, 0, stream>>>(z2,
                                             s2a + (size_t)(NLAYER - 1) * K1P,
                                             q2a + (size_t)(NLAYER - 1) * K1P,
                                             g2 + (size_t)(NLAYER - 1) * HDIM,
                                             be2 + (size_t)(NLAYER - 1) * HDIM,
                                             batch, out_h, out_pool);
}